// Round 10
// baseline (204.341 us; speedup 1.0000x reference)
//
#include <hip/hip_runtime.h>
#include <math.h>

// Problem constants (from reference)
constexpr int N = 50000, E = 800000, F = 512, P = 128, G = 256, H = 256, T = 24;
// Capacity caps (expected: ~16 edges->target, ~290 2-hop edges, ~300 nodes)
constexpr int CAPA = 4096, CAPB = 32768, CAPP = 2048, CAPH = 512;

// Workspace layout (bytes), 64-aligned
constexpr size_t OFF_DEG   = 0;        // float[N]
constexpr size_t OFF_CNT   = 200704;   // int[16]: 0=cntA,1=cntB,2=cntP,3=cntH,4..11=xcd tickets,12=winner
constexpr size_t OFF_COMM  = 200768;   // ull[2][256] tagged h-words (ping-pong)
constexpr size_t OFF_FH1   = 204864;   // uchar[N]
constexpr size_t OFF_FP    = 254912;   // uchar[N]
constexpr size_t ZERO_END  = 304960;   // memset [0, ZERO_END)
constexpr size_t OFF_IDXP  = 304960;   // int[N]
constexpr size_t OFF_IDXH1 = 504960;   // int[N]
constexpr size_t OFF_SRCA  = 704960;   // int[CAPA]
constexpr size_t OFF_WA    = 721344;   // float[CAPA]
constexpr size_t OFF_SRCB  = 737728;   // int[CAPB]
constexpr size_t OFF_DSTB  = 868800;   // int[CAPB]
constexpr size_t OFF_WB    = 999872;   // float[CAPB] (pre-normalized by src degree)
constexpr size_t OFF_LISTP = 1130944;  // int[CAPP]
constexpr size_t OFF_LISTH = 1139136;  // int[CAPH]
constexpr size_t OFF_Q     = 1141184;  // float[CAPP*G]
constexpr size_t OFF_RS    = 3238336;  // float[CAPH*G]
constexpr size_t OFF_EMB   = 3762624;  // float[2G] (only [0:256] used)
constexpr size_t OFF_XPROJ = 3764672;  // float[T*4H]

__device__ __forceinline__ float sigmoidf_(float x) { return 1.0f / (1.0f + expf(-x)); }
// Fast forms via v_exp_f32 + v_rcp_f32 (~2 ulp, fine vs 1.4e-2 threshold)
__device__ __forceinline__ float fsig_(float x) {
    return __builtin_amdgcn_rcpf(1.0f + __expf(-x));
}
__device__ __forceinline__ float ftanh_(float x) {
    return 1.0f - 2.0f * __builtin_amdgcn_rcpf(1.0f + __expf(2.0f * x));
}

// Non-temporal load: documented stream/no-allocate. If it truly skips L1
// allocation, polls always read the XCD-shared L2 (~90ns RTT). R9 ERRATum:
// sc0-only loads can hit a stale L1 line forever (hang) — so this path is
// only used with a bounded-try fallback to proven agent-scope loads.
__device__ __forceinline__ unsigned long long load_nt(const unsigned long long* p) {
    unsigned long long r;
    asm volatile("global_load_dwordx2 %0, %1, off nt\n\ts_waitcnt vmcnt(0)"
                 : "=v"(r) : "v"(p) : "memory");
    return r;
}

// Pass 1: degree accumulation + collect edges whose dst == target; flag 1-hop srcs.
__global__ void k_deg_scan(const int* __restrict__ ei, const float* __restrict__ eg,
                           const int* __restrict__ ptgt, float* __restrict__ deg,
                           int* __restrict__ cnt, unsigned char* __restrict__ fH1,
                           int* __restrict__ srcA, float* __restrict__ wA) {
    int target = *ptgt;
    int e = blockIdx.x * 256 + threadIdx.x;
    if (e < E) {
        int d = ei[E + e];
        float w = eg[e];
        atomicAdd(&deg[d], w);
        if (d == target) {
            int s = ei[e];
            int slot = atomicAdd(&cnt[0], 1);
            if (slot < CAPA) { srcA[slot] = s; wA[slot] = w; }
            fH1[s] = 1;
        }
    }
    if (blockIdx.x == 0 && threadIdx.x == 0) fH1[target] = 1;
}

// Pass 2: collect edges whose dst is a needed-h1 node (weights pre-normalized by
// src degree: wB = w * rsqrt(deg[src]+1)); flag srcs as needing p/q.
__global__ void k_scan2(const int* __restrict__ ei, const float* __restrict__ eg,
                        const float* __restrict__ deg,
                        const unsigned char* __restrict__ fH1, unsigned char* __restrict__ fP,
                        int* __restrict__ cnt, int* __restrict__ srcB,
                        int* __restrict__ dstB, float* __restrict__ wB) {
    int e = blockIdx.x * 256 + threadIdx.x;
    if (e >= E) return;
    int d = ei[E + e];
    if (fH1[d]) {
        int s = ei[e];
        float w = eg[e];
        int slot = atomicAdd(&cnt[1], 1);
        if (slot < CAPB) {
            srcB[slot] = s; dstB[slot] = d;
            wB[slot] = w * rsqrtf(deg[s] + 1.0f);
        }
        fP[s] = 1;
    }
}

// Compact flagged node sets into lists with index maps.
__global__ void k_compact(const unsigned char* __restrict__ fH1, const unsigned char* __restrict__ fP,
                          int* __restrict__ cnt, int* __restrict__ listP, int* __restrict__ listH,
                          int* __restrict__ idxP, int* __restrict__ idxH1) {
    int n = blockIdx.x * 256 + threadIdx.x;
    if (n >= N) return;
    if (fH1[n]) {
        int sh = atomicAdd(&cnt[3], 1);
        if (sh < CAPH) listH[sh] = n;
        idxH1[n] = sh;
    }
    if (fP[n] || fH1[n]) {
        int sp = atomicAdd(&cnt[2], 1);
        if (sp < CAPP) listP[sp] = n;
        idxP[n] = sp;
    }
}

// q[row] = relu((x[n]*feat_gate) @ W_proj + b_proj) @ W_g1.
// 256 blocks, round-robin rows (all blocks active), deep unroll.
__global__ void k_pq(const float* __restrict__ x, const float* __restrict__ fgate,
                     const float* __restrict__ Wproj, const float* __restrict__ bproj,
                     const float* __restrict__ Wg1, const int* __restrict__ cnt,
                     const int* __restrict__ listP, float* __restrict__ q) {
    __shared__ float xm[F];
    __shared__ float part[256];
    __shared__ float pv[P];
    int nP = min(cnt[2], CAPP);
    int tid = threadIdx.x;  // 256
    for (int row = blockIdx.x; row < nP; row += 256) {
        int n = listP[row];
        __syncthreads();  // protect LDS reuse across row iterations
        for (int i = tid; i < F; i += 256) xm[i] = x[(size_t)n * F + i] * fgate[i];
        __syncthreads();
        int col = tid & 127, kh = tid >> 7;
        const float* wp = Wproj + (size_t)(kh * 256) * P + col;
        const float* xh = xm + kh * 256;
        float acc = 0.0f;
        #pragma unroll 16
        for (int k = 0; k < 256; k++) acc += xh[k] * wp[(size_t)k * P];
        part[tid] = acc;
        __syncthreads();
        if (tid < P) pv[tid] = fmaxf(part[tid] + part[tid + 128] + bproj[tid], 0.0f);
        __syncthreads();
        float a = 0.0f;
        #pragma unroll 16
        for (int k = 0; k < P; k++) a += pv[k] * Wg1[k * G + tid];
        q[(size_t)row * G + tid] = a;
    }
}

// h1 for 1-hop-set nodes, then r = h1 @ W_g2. Edge list staged through LDS.
// Also capture h1[target] -> emb[0:256].
__global__ void k_h1(const int* __restrict__ ptgt, const float* __restrict__ deg,
                     const int* __restrict__ cnt, const int* __restrict__ listH,
                     const int* __restrict__ idxP, const int* __restrict__ srcB,
                     const int* __restrict__ dstB, const float* __restrict__ wB,
                     const float* __restrict__ q, const float* __restrict__ bg1,
                     const float* __restrict__ Wg2,
                     float* __restrict__ rs, float* __restrict__ emb) {
    __shared__ float h1row[G];
    __shared__ int ldst[512];
    __shared__ int lsrc[512];
    __shared__ float lw[512];
    int b = blockIdx.x;
    int nH = min(cnt[3], CAPH);
    if (b >= nH) return;
    int n = listH[b];
    int target = *ptgt;
    int g = threadIdx.x;  // 256 threads
    float dn = rsqrtf(deg[n] + 1.0f);
    float acc = bg1[g] + q[(size_t)idxP[n] * G + g] * dn * dn;
    int nB = min(cnt[1], CAPB);
    for (int base = 0; base < nB; base += 512) {
        int m = min(512, nB - base);
        __syncthreads();
        for (int i = g; i < m; i += 256) {
            ldst[i] = dstB[base + i]; lsrc[i] = srcB[base + i]; lw[i] = wB[base + i];
        }
        __syncthreads();
        for (int e = 0; e < m; e++) {
            if (ldst[e] == n)
                acc += lw[e] * dn * q[(size_t)idxP[lsrc[e]] * G + g];
        }
    }
    float hv = fmaxf(acc, 0.0f);
    h1row[g] = hv;
    if (n == target) emb[g] = hv;
    __syncthreads();
    float r = 0.0f;
    #pragma unroll 8
    for (int k = 0; k < G; k++) r += h1row[k] * Wg2[k * G + g];
    rs[(size_t)b * G + g] = r;
}

// xproj[t][j] = seq[t] @ W_ih[:,j] + b_ih[j] + b_hh[j]; seq built in-LDS from
// cached + emb (h1 target) + h2 target (recomputed redundantly per block).
// 32 blocks x 256 threads; block owns 32 columns, all T rows.
__global__ void k_xproj(const float* __restrict__ cached, const float* __restrict__ emb,
                        const int* __restrict__ ptgt, const int* __restrict__ pepos,
                        const float* __restrict__ deg, const int* __restrict__ cnt,
                        const int* __restrict__ idxH1, const int* __restrict__ srcA,
                        const float* __restrict__ wA, const float* __restrict__ rs,
                        const float* __restrict__ bg2,
                        const float* __restrict__ Wih, const float* __restrict__ bih,
                        const float* __restrict__ bhh, float* __restrict__ xproj) {
    __shared__ float s[T][2 * G];  // 48 KB
    int tid = threadIdx.x;
    int epos = *pepos;
    for (int i = tid; i < T * 2 * G; i += 256) {
        int t = i >> 9, k = i & 511;
        s[t][k] = (t == epos && k < G) ? emb[k] : cached[i];
    }
    // h2[target] (redundant per block, ~16 edges)
    int target = *ptgt;
    float dt = rsqrtf(deg[target] + 1.0f);
    float h2v = 0.0f;
    if (tid < G) {
        int it = idxH1[target];
        h2v = bg2[tid] + rs[(size_t)it * G + tid] * dt * dt;
        int nA = min(cnt[0], CAPA);
        for (int e = 0; e < nA; e++) {
            int sn = srcA[e];
            h2v += rsqrtf(deg[sn] + 1.0f) * wA[e] * dt * rs[(size_t)idxH1[sn] * G + tid];
        }
    }
    __syncthreads();
    if (tid < G) s[epos][G + tid] = fmaxf(h2v, 0.0f);
    __syncthreads();
    int col = blockIdx.x * 32 + (tid & 31);
    int tg = tid >> 5;  // 0..7
    float base = bih[col] + bhh[col];
    float acc[3];
    #pragma unroll
    for (int i = 0; i < 3; i++) acc[i] = base;
    #pragma unroll 16
    for (int k = 0; k < 2 * G; k++) {
        float wv = Wih[k * 4 * H + col];
        #pragma unroll
        for (int i = 0; i < 3; i++) acc[i] += s[tg + i * 8][k] * wv;
    }
    #pragma unroll
    for (int i = 0; i < 3; i++) xproj[(tg + i * 8) * 4 * H + col] = acc[i];
}

// LSTM over 4 cooperating WGs x 256 threads on ONE XCD (ticket/crown claim, R7).
// Thread owns gate column (tid>>6)*H + role*64 + (tid&63); its 256-element W_hh
// column lives in 16 named fv16 register vectors.
// R10 change: pollers try NON-TEMPORAL loads (no L1 allocate -> reads hit the
// XCD-shared L2, ~90ns). Bounded probe: if step 0 needs >64 nt polls, the
// thread permanently falls back to proven agent-scope loads (R8 semantics) —
// no-hang guarantee, worst case == R8.
typedef float fv16 __attribute__((ext_vector_type(16)));

#define LDE(J,Eidx) wv##J[Eidx] = Whh[(size_t)((J) * 16 + (Eidx)) * 1024 + col];
#define LDV(J) LDE(J,0) LDE(J,1) LDE(J,2) LDE(J,3) LDE(J,4) LDE(J,5) LDE(J,6) LDE(J,7) \
               LDE(J,8) LDE(J,9) LDE(J,10) LDE(J,11) LDE(J,12) LDE(J,13) LDE(J,14) LDE(J,15)

#define DOT4(J,Q,ACC) { float4 h4 = hb4[(J) * 4 + (Q)]; \
    ACC += h4.x * wv##J[4*(Q)] + h4.y * wv##J[4*(Q)+1] \
         + h4.z * wv##J[4*(Q)+2] + h4.w * wv##J[4*(Q)+3]; }
#define DOTV(J) DOT4(J,0,a0) DOT4(J,1,a1) DOT4(J,2,a2) DOT4(J,3,a3)

__global__ __launch_bounds__(256, 1) void k_lstm(
        const float* __restrict__ Whh, const float* __restrict__ xproj,
        unsigned long long* __restrict__ comm, int* __restrict__ ctrl,
        const float* __restrict__ Watt, const float* __restrict__ batt,
        const float* __restrict__ Wp1, const float* __restrict__ bp1,
        const float* __restrict__ Wp2, const float* __restrict__ bp2,
        float* __restrict__ out) {
    __shared__ __align__(16) float hbuf[H];   // 1 KB
    __shared__ float glds[4 * 64];            // gate exchange
    __shared__ float rnn_lds[T][H];           // 24 KB (role-0 tail)
    __shared__ float sc[T];
    __shared__ float attw[T];
    __shared__ float ctx_l[H];
    __shared__ float watt_l[H];
    __shared__ float part[256];
    __shared__ float hid_l[64];
    __shared__ float wp2_l[64];
    __shared__ int role_s;

    int tid = threadIdx.x;     // 0..255

    // ---- same-XCD role claiming ----
    if (tid == 0) {
        int xcd;
        asm volatile("s_getreg_b32 %0, hwreg(HW_REG_XCC_ID)" : "=s"(xcd));
        xcd &= 7;
        int role = -1;
        int ticket = __hip_atomic_fetch_add(&ctrl[xcd], 1, __ATOMIC_RELAXED,
                                            __HIP_MEMORY_SCOPE_AGENT);
        if (ticket < 4) {
            if (ticket == 3) {  // 4th claimant on this XCD: try to crown it
                int expected = 0;
                __hip_atomic_compare_exchange_strong(&ctrl[8], &expected, xcd + 1,
                        __ATOMIC_RELAXED, __ATOMIC_RELAXED, __HIP_MEMORY_SCOPE_AGENT);
            }
            int wnr;
            do {
                wnr = __hip_atomic_load(&ctrl[8], __ATOMIC_RELAXED, __HIP_MEMORY_SCOPE_AGENT);
                __builtin_amdgcn_s_sleep(1);
            } while (wnr == 0);
            if (wnr == xcd + 1) role = ticket;
        }
        role_s = role;
    }
    __syncthreads();
    int w = role_s;
    if (w < 0) return;
    int l = tid & 63;                       // local channel
    int col = (tid >> 6) * H + w * 64 + l;  // global gate column

    // Preload this thread's W_hh column into 256 register lanes (coalesced).
    fv16 wv0, wv1, wv2, wv3, wv4, wv5, wv6, wv7;
    fv16 wv8, wv9, wv10, wv11, wv12, wv13, wv14, wv15;
    LDV(0) LDV(1) LDV(2) LDV(3) LDV(4) LDV(5) LDV(6) LDV(7)
    LDV(8) LDV(9) LDV(10) LDV(11) LDV(12) LDV(13) LDV(14) LDV(15)

    // This thread's poll assignment: one foreign word (tid<192).
    int pch = tid + (tid >= w * 64 ? 64 : 0);

    const float4* hb4 = (const float4*)hbuf;
    hbuf[tid] = 0.0f;
    float cstate = 0.0f;            // live in tid < 64
    float xnext = xproj[col];       // prefetch t=0
    bool use_agent = false;         // nt-probe fallback state (persists across steps)
    __syncthreads();

    for (int t = 0; t < T; t++) {
        float xt = xnext;
        if (t + 1 < T) xnext = xproj[(t + 1) * 4 * H + col];  // in flight during dot
        float a0 = 0.0f, a1 = 0.0f, a2 = 0.0f, a3 = 0.0f;
        DOTV(0) DOTV(1) DOTV(2) DOTV(3) DOTV(4) DOTV(5) DOTV(6) DOTV(7)
        DOTV(8) DOTV(9) DOTV(10) DOTV(11) DOTV(12) DOTV(13) DOTV(14) DOTV(15)
        glds[tid] = ((a0 + a1) + (a2 + a3)) + xt;
        __syncthreads();
        int s = t + 1;
        // publishers: compute own 64 channels, store (agent) FIRST, then LDS.
        if (tid < 64) {
            float gi = glds[l], gf = glds[64 + l], gg = glds[128 + l], go = glds[192 + l];
            cstate = fsig_(gf) * cstate + fsig_(gi) * ftanh_(gg);
            float hv = fsig_(go) * ftanh_(cstate);
            unsigned long long word =
                ((unsigned long long)__float_as_uint(hv) << 32) | (unsigned)s;
            __hip_atomic_store(&comm[(size_t)(s & 1) * 256 + w * 64 + l], word,
                               __ATOMIC_RELAXED, __HIP_MEMORY_SCOPE_AGENT);
            hbuf[w * 64 + l] = hv;   // own channels direct to LDS
        }
        // pollers: one thread per foreign word. nt loads (L2-local) with a
        // bounded step-0 probe; fallback = proven agent loads (R8).
        if (tid < 192) {
            const unsigned long long* cp = &comm[(size_t)(s & 1) * 256 + pch];
            unsigned long long wd;
            if (!use_agent) {
                wd = load_nt(cp);
                int tries = 0;
                while ((unsigned)wd != (unsigned)s) {
                    if (++tries > 64) { use_agent = true; break; }
                    wd = load_nt(cp);
                }
            }
            if (use_agent) {
                wd = __hip_atomic_load(cp, __ATOMIC_RELAXED, __HIP_MEMORY_SCOPE_AGENT);
                while ((unsigned)wd != (unsigned)s) {
                    __builtin_amdgcn_s_sleep(1);
                    wd = __hip_atomic_load(cp, __ATOMIC_RELAXED, __HIP_MEMORY_SCOPE_AGENT);
                }
            }
            hbuf[pch] = __uint_as_float((unsigned)(wd >> 32));
        }
        __syncthreads();
        if (w == 0) rnn_lds[t][tid] = hbuf[tid];
    }

    if (w != 0) return;
    // ---- attention + MLP tail (role 0 only) ----
    watt_l[tid] = Watt[tid];
    if (tid < 64) wp2_l[tid] = Wp2[tid];
    __syncthreads();
    if (tid < T) {
        float sv = 0.0f;
        #pragma unroll 8
        for (int h = 0; h < H; h++) sv += rnn_lds[tid][h] * watt_l[h];
        sc[tid] = tanhf(sv + batt[0]);
    }
    __syncthreads();
    if (tid == 0) {
        float m = -1e30f;
        for (int t = 0; t < T; t++) m = fmaxf(m, sc[t]);
        float su = 0.0f;
        for (int t = 0; t < T; t++) { float e = expf(sc[t] - m); attw[t] = e; su += e; }
        float inv = 1.0f / su;
        for (int t = 0; t < T; t++) attw[t] *= inv;
    }
    __syncthreads();
    {
        float a = 0.0f;
        #pragma unroll
        for (int t = 0; t < T; t++) a += rnn_lds[t][tid] * attw[t];
        ctx_l[tid] = a;
    }
    __syncthreads();
    {
        int col2 = tid & 63, sl = tid >> 6;  // 4 k-slices of 64
        float a = 0.0f;
        #pragma unroll 16
        for (int kk = 0; kk < 64; kk++) {
            int k = sl * 64 + kk;
            a += ctx_l[k] * Wp1[k * 64 + col2];
        }
        part[tid] = a;
    }
    __syncthreads();
    if (tid < 64) {
        float a = bp1[tid] + part[tid] + part[64 + tid] + part[128 + tid] + part[192 + tid];
        hid_l[tid] = fmaxf(a, 0.0f);
    }
    __syncthreads();
    if (tid == 0) {
        float r = bp2[0];
        #pragma unroll
        for (int j = 0; j < 64; j++) r += hid_l[j] * wp2_l[j];
        out[0] = (r > 20.0f) ? r : log1pf(expf(r));
    }
}

extern "C" void kernel_launch(void* const* d_in, const int* in_sizes, int n_in,
                              void* d_out, int out_size, void* d_ws, size_t ws_size,
                              hipStream_t stream) {
    const float* x      = (const float*)d_in[0];
    const int*   ei     = (const int*)d_in[1];
    const float* fgate  = (const float*)d_in[2];
    const float* egate  = (const float*)d_in[3];
    const float* cached = (const float*)d_in[4];
    const float* Wproj  = (const float*)d_in[5];
    const float* bproj  = (const float*)d_in[6];
    const float* Wg1    = (const float*)d_in[7];
    const float* bg1    = (const float*)d_in[8];
    const float* Wg2    = (const float*)d_in[9];
    const float* bg2    = (const float*)d_in[10];
    const float* Wih    = (const float*)d_in[11];
    const float* Whh    = (const float*)d_in[12];
    const float* bih    = (const float*)d_in[13];
    const float* bhh    = (const float*)d_in[14];
    const float* Watt   = (const float*)d_in[15];
    const float* batt   = (const float*)d_in[16];
    const float* Wp1    = (const float*)d_in[17];
    const float* bp1    = (const float*)d_in[18];
    const float* Wp2    = (const float*)d_in[19];
    const float* bp2    = (const float*)d_in[20];
    const int*   ptgt   = (const int*)d_in[21];
    const int*   pepos  = (const int*)d_in[22];

    char* ws = (char*)d_ws;
    float* deg   = (float*)(ws + OFF_DEG);
    int*   cnt   = (int*)(ws + OFF_CNT);
    unsigned long long* comm = (unsigned long long*)(ws + OFF_COMM);
    unsigned char* fH1 = (unsigned char*)(ws + OFF_FH1);
    unsigned char* fP  = (unsigned char*)(ws + OFF_FP);
    int*   idxP  = (int*)(ws + OFF_IDXP);
    int*   idxH1 = (int*)(ws + OFF_IDXH1);
    int*   srcA  = (int*)(ws + OFF_SRCA);
    float* wA    = (float*)(ws + OFF_WA);
    int*   srcB  = (int*)(ws + OFF_SRCB);
    int*   dstB  = (int*)(ws + OFF_DSTB);
    float* wB    = (float*)(ws + OFF_WB);
    int*   listP = (int*)(ws + OFF_LISTP);
    int*   listH = (int*)(ws + OFF_LISTH);
    float* q     = (float*)(ws + OFF_Q);
    float* rs    = (float*)(ws + OFF_RS);
    float* emb   = (float*)(ws + OFF_EMB);
    float* xproj = (float*)(ws + OFF_XPROJ);

    hipMemsetAsync(ws, 0, ZERO_END, stream);

    k_deg_scan<<<(E + 255) / 256, 256, 0, stream>>>(ei, egate, ptgt, deg, cnt, fH1, srcA, wA);
    k_scan2<<<(E + 255) / 256, 256, 0, stream>>>(ei, egate, deg, fH1, fP, cnt, srcB, dstB, wB);
    k_compact<<<(N + 255) / 256, 256, 0, stream>>>(fH1, fP, cnt, listP, listH, idxP, idxH1);
    k_pq<<<256, 256, 0, stream>>>(x, fgate, Wproj, bproj, Wg1, cnt, listP, q);
    k_h1<<<CAPH, 256, 0, stream>>>(ptgt, deg, cnt, listH, idxP, srcB, dstB, wB, q, bg1, Wg2, rs, emb);
    k_xproj<<<32, 256, 0, stream>>>(cached, emb, ptgt, pepos, deg, cnt, idxH1, srcA, wA, rs, bg2,
                                    Wih, bih, bhh, xproj);
    k_lstm<<<64, 256, 0, stream>>>(Whh, xproj, comm, cnt + 4, Watt, batt, Wp1, bp1, Wp2, bp2,
                                   (float*)d_out);
}

// Round 11
// 154.861 us; speedup vs baseline: 1.3195x; 1.3195x over previous
//
#include <hip/hip_runtime.h>
#include <math.h>

// Problem constants (from reference)
constexpr int N = 50000, E = 800000, F = 512, P = 128, G = 256, H = 256, T = 24;
// Capacity caps (expected: ~16 edges->target, ~290 2-hop edges, ~300 nodes)
constexpr int CAPA = 4096, CAPB = 32768, CAPP = 2048, CAPH = 512;

// Workspace layout (bytes), 64-aligned
constexpr size_t OFF_DEG   = 0;        // float[N]
constexpr size_t OFF_CNT   = 200704;   // int[16]: 0=cntA,1=cntB,2=cntP,3=cntH; +4: ctrl[0..7]=xcd tickets,
                                       //   ctrl[8]=winner, ctrl[9]=slice ticket, ctrl[10]=xproj done
constexpr size_t OFF_COMM  = 200768;   // ull[2][256] tagged h-words (ping-pong)
constexpr size_t OFF_FH1   = 204864;   // uchar[N]
constexpr size_t OFF_FP    = 254912;   // uchar[N]
constexpr size_t ZERO_END  = 304960;   // memset [0, ZERO_END)
constexpr size_t OFF_IDXP  = 304960;   // int[N]
constexpr size_t OFF_IDXH1 = 504960;   // int[N]
constexpr size_t OFF_SRCA  = 704960;   // int[CAPA]
constexpr size_t OFF_WA    = 721344;   // float[CAPA]
constexpr size_t OFF_SRCB  = 737728;   // int[CAPB]
constexpr size_t OFF_DSTB  = 868800;   // int[CAPB]
constexpr size_t OFF_WB    = 999872;   // float[CAPB] (RAW edge gate; normalized in k_h1)
constexpr size_t OFF_LISTP = 1130944;  // int[CAPP]
constexpr size_t OFF_LISTH = 1139136;  // int[CAPH]
constexpr size_t OFF_Q     = 1141184;  // float[CAPP*G]
constexpr size_t OFF_RS    = 3238336;  // float[CAPH*G]
constexpr size_t OFF_EMB   = 3762624;  // float[2G] (only [0:256] used)
constexpr size_t OFF_XPROJ = 3764672;  // float[T*4H]

// Fast gate forms via v_exp_f32 + v_rcp_f32 (~2 ulp, fine vs 1.4e-2 threshold)
__device__ __forceinline__ float fsig_(float x) {
    return __builtin_amdgcn_rcpf(1.0f + __expf(-x));
}
__device__ __forceinline__ float ftanh_(float x) {
    return 1.0f - 2.0f * __builtin_amdgcn_rcpf(1.0f + __expf(2.0f * x));
}

// Pass 1: collect edges whose dst == target; flag 1-hop srcs. NO deg atomics
// (deg is only needed for ~320 nodes; accumulated selectively in scan2/scan3).
__global__ void k_scan1(const int* __restrict__ ei, const float* __restrict__ eg,
                        const int* __restrict__ ptgt, int* __restrict__ cnt,
                        unsigned char* __restrict__ fH1,
                        int* __restrict__ srcA, float* __restrict__ wA) {
    int target = *ptgt;
    int base = (blockIdx.x * 256 + threadIdx.x) * 4;
    if (base < E) {
        int4 d4 = *(const int4*)&ei[E + base];
        int dd0 = d4.x, dd1 = d4.y, dd2 = d4.z, dd3 = d4.w;
        #pragma unroll
        for (int j = 0; j < 4; j++) {
            int d = (j == 0) ? dd0 : (j == 1) ? dd1 : (j == 2) ? dd2 : dd3;
            if (d == target) {
                int e = base + j;
                int s = ei[e];
                int slot = atomicAdd(&cnt[0], 1);
                if (slot < CAPA) { srcA[slot] = s; wA[slot] = eg[e]; }
                fH1[s] = 1;
            }
        }
    }
    if (blockIdx.x == 0 && threadIdx.x == 0) fH1[target] = 1;
}

// Pass 2: collect edges whose dst is a needed-h1 node; flag srcs; accumulate
// deg for fH1 dsts (these edges ARE all edges into fH1 nodes; ~290 atomics).
__global__ void k_scan2(const int* __restrict__ ei, const float* __restrict__ eg,
                        const unsigned char* __restrict__ fH1, unsigned char* __restrict__ fP,
                        int* __restrict__ cnt, int* __restrict__ srcB,
                        int* __restrict__ dstB, float* __restrict__ wB,
                        float* __restrict__ deg) {
    int base = (blockIdx.x * 256 + threadIdx.x) * 4;
    if (base >= E) return;
    int4 d4 = *(const int4*)&ei[E + base];
    int dd0 = d4.x, dd1 = d4.y, dd2 = d4.z, dd3 = d4.w;
    #pragma unroll
    for (int j = 0; j < 4; j++) {
        int d = (j == 0) ? dd0 : (j == 1) ? dd1 : (j == 2) ? dd2 : dd3;
        if (fH1[d]) {
            int e = base + j;
            int s = ei[e];
            float w = eg[e];
            int slot = atomicAdd(&cnt[1], 1);
            if (slot < CAPB) { srcB[slot] = s; dstB[slot] = d; wB[slot] = w; }
            fP[s] = 1;
            atomicAdd(&deg[d], w);
        }
    }
}

// Pass 3 (fused): deg for fP-only dsts (~5K atomics) + node compaction.
__global__ void k_scan3c(const int* __restrict__ ei, const float* __restrict__ eg,
                         const unsigned char* __restrict__ fH1, const unsigned char* __restrict__ fP,
                         float* __restrict__ deg, int* __restrict__ cnt,
                         int* __restrict__ listP, int* __restrict__ listH,
                         int* __restrict__ idxP, int* __restrict__ idxH1) {
    int base = (blockIdx.x * 256 + threadIdx.x) * 4;
    if (base < E) {
        int4 d4 = *(const int4*)&ei[E + base];
        int dd0 = d4.x, dd1 = d4.y, dd2 = d4.z, dd3 = d4.w;
        #pragma unroll
        for (int j = 0; j < 4; j++) {
            int d = (j == 0) ? dd0 : (j == 1) ? dd1 : (j == 2) ? dd2 : dd3;
            if (fP[d] && !fH1[d]) atomicAdd(&deg[d], eg[base + j]);
        }
    }
    int n = blockIdx.x * 256 + threadIdx.x;
    if (n < N) {
        if (fH1[n]) {
            int sh = atomicAdd(&cnt[3], 1);
            if (sh < CAPH) listH[sh] = n;
            idxH1[n] = sh;
        }
        if (fP[n] || fH1[n]) {
            int sp = atomicAdd(&cnt[2], 1);
            if (sp < CAPP) listP[sp] = n;
            idxP[n] = sp;
        }
    }
}

// q[row] = relu((x[n]*feat_gate) @ W_proj + b_proj) @ W_g1.
// 256 blocks, round-robin rows (all blocks active), deep unroll.
__global__ void k_pq(const float* __restrict__ x, const float* __restrict__ fgate,
                     const float* __restrict__ Wproj, const float* __restrict__ bproj,
                     const float* __restrict__ Wg1, const int* __restrict__ cnt,
                     const int* __restrict__ listP, float* __restrict__ q) {
    __shared__ float xm[F];
    __shared__ float part[256];
    __shared__ float pv[P];
    int nP = min(cnt[2], CAPP);
    int tid = threadIdx.x;  // 256
    for (int row = blockIdx.x; row < nP; row += 256) {
        int n = listP[row];
        __syncthreads();  // protect LDS reuse across row iterations
        for (int i = tid; i < F; i += 256) xm[i] = x[(size_t)n * F + i] * fgate[i];
        __syncthreads();
        int col = tid & 127, kh = tid >> 7;
        const float* wp = Wproj + (size_t)(kh * 256) * P + col;
        const float* xh = xm + kh * 256;
        float acc = 0.0f;
        #pragma unroll 16
        for (int k = 0; k < 256; k++) acc += xh[k] * wp[(size_t)k * P];
        part[tid] = acc;
        __syncthreads();
        if (tid < P) pv[tid] = fmaxf(part[tid] + part[tid + 128] + bproj[tid], 0.0f);
        __syncthreads();
        float a = 0.0f;
        #pragma unroll 16
        for (int k = 0; k < P; k++) a += pv[k] * Wg1[k * G + tid];
        q[(size_t)row * G + tid] = a;
    }
}

// h1 for 1-hop-set nodes, then r = h1 @ W_g2. Edge list staged through LDS,
// with src-degree normalization applied at staging time (deg complete now).
__global__ void k_h1(const int* __restrict__ ptgt, const float* __restrict__ deg,
                     const int* __restrict__ cnt, const int* __restrict__ listH,
                     const int* __restrict__ idxP, const int* __restrict__ srcB,
                     const int* __restrict__ dstB, const float* __restrict__ wB,
                     const float* __restrict__ q, const float* __restrict__ bg1,
                     const float* __restrict__ Wg2,
                     float* __restrict__ rs, float* __restrict__ emb) {
    __shared__ float h1row[G];
    __shared__ int ldst[512];
    __shared__ int lsrc[512];
    __shared__ float lw[512];
    int b = blockIdx.x;
    int nH = min(cnt[3], CAPH);
    if (b >= nH) return;
    int n = listH[b];
    int target = *ptgt;
    int g = threadIdx.x;  // 256 threads
    float dn = rsqrtf(deg[n] + 1.0f);
    float acc = bg1[g] + q[(size_t)idxP[n] * G + g] * dn * dn;
    int nB = min(cnt[1], CAPB);
    for (int base = 0; base < nB; base += 512) {
        int m = min(512, nB - base);
        __syncthreads();
        for (int i = g; i < m; i += 256) {
            int s2 = srcB[base + i];
            ldst[i] = dstB[base + i];
            lsrc[i] = s2;
            lw[i] = wB[base + i] * rsqrtf(deg[s2] + 1.0f);
        }
        __syncthreads();
        for (int e = 0; e < m; e++) {
            if (ldst[e] == n)
                acc += lw[e] * dn * q[(size_t)idxP[lsrc[e]] * G + g];
        }
    }
    float hv = fmaxf(acc, 0.0f);
    h1row[g] = hv;
    if (n == target) emb[g] = hv;
    __syncthreads();
    float r = 0.0f;
    #pragma unroll 8
    for (int k = 0; k < G; k++) r += h1row[k] * Wg2[k * G + g];
    rs[(size_t)b * G + g] = r;
}

// LSTM + fused xproj. 64 WGs x 256 threads:
//  - 4 winner WGs on ONE XCD (ticket/crown claim, R7) run the LSTM; thread owns
//    gate column (tid>>6)*H + role*64 + (tid&63) with its 256-element W_hh column
//    in 16 named fv16 register vectors. Exchange = R8's proven tagged agent
//    atomics + s_sleep backoff (five mechanisms all measured ~2.7-2.9us/step:
//    architectural cross-CU visibility floor).
//  - 32 loser WGs compute xproj slices (seq built from cached+emb+h2), then
//    RELEASE-increment ctrl[10]; winners ACQUIRE-wait before reading xproj.
//    Overlaps xproj with the winners' W_hh preload; kills the k_xproj dispatch.
typedef float fv16 __attribute__((ext_vector_type(16)));

#define LDE(J,Eidx) wv##J[Eidx] = Whh[(size_t)((J) * 16 + (Eidx)) * 1024 + col];
#define LDV(J) LDE(J,0) LDE(J,1) LDE(J,2) LDE(J,3) LDE(J,4) LDE(J,5) LDE(J,6) LDE(J,7) \
               LDE(J,8) LDE(J,9) LDE(J,10) LDE(J,11) LDE(J,12) LDE(J,13) LDE(J,14) LDE(J,15)

#define DOT4(J,Q,ACC) { float4 h4 = hb4[(J) * 4 + (Q)]; \
    ACC += h4.x * wv##J[4*(Q)] + h4.y * wv##J[4*(Q)+1] \
         + h4.z * wv##J[4*(Q)+2] + h4.w * wv##J[4*(Q)+3]; }
#define DOTV(J) DOT4(J,0,a0) DOT4(J,1,a1) DOT4(J,2,a2) DOT4(J,3,a3)

__global__ __launch_bounds__(256, 1) void k_lstm(
        const float* __restrict__ Whh, const float* __restrict__ cached,
        const float* __restrict__ emb, const int* __restrict__ ptgt,
        const int* __restrict__ pepos, const float* __restrict__ deg,
        int* __restrict__ cnt, const int* __restrict__ idxH1,
        const int* __restrict__ srcA, const float* __restrict__ wA,
        const float* __restrict__ rs, const float* __restrict__ bg2,
        const float* __restrict__ Wih, const float* __restrict__ bih,
        const float* __restrict__ bhh, float* __restrict__ xproj,
        unsigned long long* __restrict__ comm,
        const float* __restrict__ Watt, const float* __restrict__ batt,
        const float* __restrict__ Wp1, const float* __restrict__ bp1,
        const float* __restrict__ Wp2, const float* __restrict__ bp2,
        float* __restrict__ out) {
    __shared__ __align__(16) char smem[49152];   // overlaid: xproj seq OR lstm arrays
    __shared__ int role_s;
    __shared__ int slice_s;

    int* ctrl = cnt + 4;
    int tid = threadIdx.x;     // 0..255

    // ---- same-XCD role claiming ----
    if (tid == 0) {
        int xcd;
        asm volatile("s_getreg_b32 %0, hwreg(HW_REG_XCC_ID)" : "=s"(xcd));
        xcd &= 7;
        int role = -1;
        int ticket = __hip_atomic_fetch_add(&ctrl[xcd], 1, __ATOMIC_RELAXED,
                                            __HIP_MEMORY_SCOPE_AGENT);
        if (ticket < 4) {
            if (ticket == 3) {  // 4th claimant on this XCD: try to crown it
                int expected = 0;
                __hip_atomic_compare_exchange_strong(&ctrl[8], &expected, xcd + 1,
                        __ATOMIC_RELAXED, __ATOMIC_RELAXED, __HIP_MEMORY_SCOPE_AGENT);
            }
            int wnr;
            do {
                wnr = __hip_atomic_load(&ctrl[8], __ATOMIC_RELAXED, __HIP_MEMORY_SCOPE_AGENT);
                __builtin_amdgcn_s_sleep(1);
            } while (wnr == 0);
            if (wnr == xcd + 1) role = ticket;
        }
        role_s = role;
    }
    __syncthreads();
    int w = role_s;

    if (w < 0) {
        // ---- loser path: take an xproj slice (32 slices of 32 columns) ----
        if (tid == 0)
            slice_s = __hip_atomic_fetch_add(&ctrl[9], 1, __ATOMIC_RELAXED,
                                             __HIP_MEMORY_SCOPE_AGENT);
        __syncthreads();
        int sl = slice_s;
        if (sl >= 32) return;
        float (*s)[2 * G] = (float(*)[2 * G])smem;  // 48 KB seq
        int epos = *pepos;
        for (int i = tid; i < T * 2 * G; i += 256) {
            int t = i >> 9, k = i & 511;
            s[t][k] = (t == epos && k < G) ? emb[k] : cached[i];
        }
        // h2[target] (redundant per slice WG, ~16 edges)
        int target = *ptgt;
        float dt = rsqrtf(deg[target] + 1.0f);
        float h2v = 0.0f;
        if (tid < G) {
            int it = idxH1[target];
            h2v = bg2[tid] + rs[(size_t)it * G + tid] * dt * dt;
            int nA = min(cnt[0], CAPA);
            for (int e = 0; e < nA; e++) {
                int sn = srcA[e];
                h2v += rsqrtf(deg[sn] + 1.0f) * wA[e] * dt * rs[(size_t)idxH1[sn] * G + tid];
            }
        }
        __syncthreads();
        if (tid < G) s[epos][G + tid] = fmaxf(h2v, 0.0f);
        __syncthreads();
        int colx = sl * 32 + (tid & 31);
        int tg = tid >> 5;  // 0..7
        float base = bih[colx] + bhh[colx];
        float a0 = base, a1 = base, a2 = base;
        #pragma unroll 16
        for (int k = 0; k < 2 * G; k++) {
            float wv = Wih[k * 4 * H + colx];
            a0 += s[tg][k] * wv; a1 += s[tg + 8][k] * wv; a2 += s[tg + 16][k] * wv;
        }
        xproj[tg * 4 * H + colx] = a0;
        xproj[(tg + 8) * 4 * H + colx] = a1;
        xproj[(tg + 16) * 4 * H + colx] = a2;
        __syncthreads();
        if (tid == 0)
            __hip_atomic_fetch_add(&ctrl[10], 1, __ATOMIC_RELEASE,
                                   __HIP_MEMORY_SCOPE_AGENT);
        return;
    }

    // ---- winner path: LSTM ----
    float* hbuf = (float*)smem;                              // [256]
    float* glds = hbuf + 256;                                // [256]
    float (*rnn_lds)[H] = (float(*)[H])(glds + 256);         // [T][256] = 24 KB
    float* tb   = (float*)smem + 512 + T * H;
    float* sc    = tb;            // [T]
    float* attw  = tb + T;        // [T]
    float* ctx_l = tb + 2 * T;    // [H]
    float* watt_l= tb + 2 * T + H;        // [H]
    float* part  = tb + 2 * T + 2 * H;    // [256]
    float* hid_l = tb + 2 * T + 2 * H + 256;  // [64]
    float* wp2_l = tb + 2 * T + 2 * H + 320;  // [64]

    int l = tid & 63;                       // local channel
    int col = (tid >> 6) * H + w * 64 + l;  // global gate column

    // Preload this thread's W_hh column into 256 register lanes (coalesced),
    // overlapping with the loser WGs' xproj computation.
    fv16 wv0, wv1, wv2, wv3, wv4, wv5, wv6, wv7;
    fv16 wv8, wv9, wv10, wv11, wv12, wv13, wv14, wv15;
    LDV(0) LDV(1) LDV(2) LDV(3) LDV(4) LDV(5) LDV(6) LDV(7)
    LDV(8) LDV(9) LDV(10) LDV(11) LDV(12) LDV(13) LDV(14) LDV(15)

    // Wait for all 32 xproj slices (acquire pairs with losers' release).
    if (tid == 0) {
        while (__hip_atomic_load(&ctrl[10], __ATOMIC_ACQUIRE,
                                 __HIP_MEMORY_SCOPE_AGENT) < 32)
            __builtin_amdgcn_s_sleep(2);
    }
    __syncthreads();

    // This thread's poll assignment: one foreign word (tid<192).
    int pch = tid + (tid >= w * 64 ? 64 : 0);

    const float4* hb4 = (const float4*)hbuf;
    hbuf[tid] = 0.0f;
    float cstate = 0.0f;            // live in tid < 64
    float xnext = xproj[col];       // prefetch t=0
    __syncthreads();

    for (int t = 0; t < T; t++) {
        float xt = xnext;
        if (t + 1 < T) xnext = xproj[(t + 1) * 4 * H + col];  // in flight during dot
        float a0 = 0.0f, a1 = 0.0f, a2 = 0.0f, a3 = 0.0f;
        DOTV(0) DOTV(1) DOTV(2) DOTV(3) DOTV(4) DOTV(5) DOTV(6) DOTV(7)
        DOTV(8) DOTV(9) DOTV(10) DOTV(11) DOTV(12) DOTV(13) DOTV(14) DOTV(15)
        glds[tid] = ((a0 + a1) + (a2 + a3)) + xt;
        __syncthreads();
        int s = t + 1;
        // publishers: compute own 64 channels, store (agent) FIRST, then LDS.
        if (tid < 64) {
            float gi = glds[l], gf = glds[64 + l], gg = glds[128 + l], go = glds[192 + l];
            cstate = fsig_(gf) * cstate + fsig_(gi) * ftanh_(gg);
            float hv = fsig_(go) * ftanh_(cstate);
            unsigned long long word =
                ((unsigned long long)__float_as_uint(hv) << 32) | (unsigned)s;
            __hip_atomic_store(&comm[(size_t)(s & 1) * 256 + w * 64 + l], word,
                               __ATOMIC_RELAXED, __HIP_MEMORY_SCOPE_AGENT);
            hbuf[w * 64 + l] = hv;   // own channels direct to LDS
        }
        // pollers: one thread per foreign word, agent loads + sleep backoff (R8).
        if (tid < 192) {
            const unsigned long long* cp = &comm[(size_t)(s & 1) * 256 + pch];
            unsigned long long wd =
                __hip_atomic_load(cp, __ATOMIC_RELAXED, __HIP_MEMORY_SCOPE_AGENT);
            while ((unsigned)wd != (unsigned)s) {
                __builtin_amdgcn_s_sleep(1);
                wd = __hip_atomic_load(cp, __ATOMIC_RELAXED, __HIP_MEMORY_SCOPE_AGENT);
            }
            hbuf[pch] = __uint_as_float((unsigned)(wd >> 32));
        }
        __syncthreads();
        if (w == 0) rnn_lds[t][tid] = hbuf[tid];
    }

    if (w != 0) return;
    // ---- attention + MLP tail (role 0 only) ----
    watt_l[tid] = Watt[tid];
    if (tid < 64) wp2_l[tid] = Wp2[tid];
    __syncthreads();
    if (tid < T) {
        float sv = 0.0f;
        #pragma unroll 8
        for (int h = 0; h < H; h++) sv += rnn_lds[tid][h] * watt_l[h];
        sc[tid] = tanhf(sv + batt[0]);
    }
    __syncthreads();
    if (tid == 0) {
        float m = -1e30f;
        for (int t = 0; t < T; t++) m = fmaxf(m, sc[t]);
        float su = 0.0f;
        for (int t = 0; t < T; t++) { float e = expf(sc[t] - m); attw[t] = e; su += e; }
        float inv = 1.0f / su;
        for (int t = 0; t < T; t++) attw[t] *= inv;
    }
    __syncthreads();
    {
        float a = 0.0f;
        #pragma unroll
        for (int t = 0; t < T; t++) a += rnn_lds[t][tid] * attw[t];
        ctx_l[tid] = a;
    }
    __syncthreads();
    {
        int col2 = tid & 63, sl2 = tid >> 6;  // 4 k-slices of 64
        float a = 0.0f;
        #pragma unroll 16
        for (int kk = 0; kk < 64; kk++) {
            int k = sl2 * 64 + kk;
            a += ctx_l[k] * Wp1[k * 64 + col2];
        }
        part[tid] = a;
    }
    __syncthreads();
    if (tid < 64) {
        float a = bp1[tid] + part[tid] + part[64 + tid] + part[128 + tid] + part[192 + tid];
        hid_l[tid] = fmaxf(a, 0.0f);
    }
    __syncthreads();
    if (tid == 0) {
        float r = bp2[0];
        #pragma unroll
        for (int j = 0; j < 64; j++) r += hid_l[j] * wp2_l[j];
        out[0] = (r > 20.0f) ? r : log1pf(expf(r));
    }
}

extern "C" void kernel_launch(void* const* d_in, const int* in_sizes, int n_in,
                              void* d_out, int out_size, void* d_ws, size_t ws_size,
                              hipStream_t stream) {
    const float* x      = (const float*)d_in[0];
    const int*   ei     = (const int*)d_in[1];
    const float* fgate  = (const float*)d_in[2];
    const float* egate  = (const float*)d_in[3];
    const float* cached = (const float*)d_in[4];
    const float* Wproj  = (const float*)d_in[5];
    const float* bproj  = (const float*)d_in[6];
    const float* Wg1    = (const float*)d_in[7];
    const float* bg1    = (const float*)d_in[8];
    const float* Wg2    = (const float*)d_in[9];
    const float* bg2    = (const float*)d_in[10];
    const float* Wih    = (const float*)d_in[11];
    const float* Whh    = (const float*)d_in[12];
    const float* bih    = (const float*)d_in[13];
    const float* bhh    = (const float*)d_in[14];
    const float* Watt   = (const float*)d_in[15];
    const float* batt   = (const float*)d_in[16];
    const float* Wp1    = (const float*)d_in[17];
    const float* bp1    = (const float*)d_in[18];
    const float* Wp2    = (const float*)d_in[19];
    const float* bp2    = (const float*)d_in[20];
    const int*   ptgt   = (const int*)d_in[21];
    const int*   pepos  = (const int*)d_in[22];

    char* ws = (char*)d_ws;
    float* deg   = (float*)(ws + OFF_DEG);
    int*   cnt   = (int*)(ws + OFF_CNT);
    unsigned long long* comm = (unsigned long long*)(ws + OFF_COMM);
    unsigned char* fH1 = (unsigned char*)(ws + OFF_FH1);
    unsigned char* fP  = (unsigned char*)(ws + OFF_FP);
    int*   idxP  = (int*)(ws + OFF_IDXP);
    int*   idxH1 = (int*)(ws + OFF_IDXH1);
    int*   srcA  = (int*)(ws + OFF_SRCA);
    float* wA    = (float*)(ws + OFF_WA);
    int*   srcB  = (int*)(ws + OFF_SRCB);
    int*   dstB  = (int*)(ws + OFF_DSTB);
    float* wB    = (float*)(ws + OFF_WB);
    int*   listP = (int*)(ws + OFF_LISTP);
    int*   listH = (int*)(ws + OFF_LISTH);
    float* q     = (float*)(ws + OFF_Q);
    float* rs    = (float*)(ws + OFF_RS);
    float* emb   = (float*)(ws + OFF_EMB);
    float* xproj = (float*)(ws + OFF_XPROJ);

    hipMemsetAsync(ws, 0, ZERO_END, stream);

    int nEB = (E / 4 + 255) / 256;  // 782 blocks, int4-vectorized edge scans
    k_scan1<<<nEB, 256, 0, stream>>>(ei, egate, ptgt, cnt, fH1, srcA, wA);
    k_scan2<<<nEB, 256, 0, stream>>>(ei, egate, fH1, fP, cnt, srcB, dstB, wB, deg);
    k_scan3c<<<nEB, 256, 0, stream>>>(ei, egate, fH1, fP, deg, cnt, listP, listH, idxP, idxH1);
    k_pq<<<256, 256, 0, stream>>>(x, fgate, Wproj, bproj, Wg1, cnt, listP, q);
    k_h1<<<CAPH, 256, 0, stream>>>(ptgt, deg, cnt, listH, idxP, srcB, dstB, wB, q, bg1, Wg2, rs, emb);
    k_lstm<<<64, 256, 0, stream>>>(Whh, cached, emb, ptgt, pepos, deg, cnt, idxH1, srcA, wA,
                                   rs, bg2, Wih, bih, bhh, xproj, comm,
                                   Watt, batt, Wp1, bp1, Wp2, bp2, (float*)d_out);
}

// Round 12
// 153.680 us; speedup vs baseline: 1.3296x; 1.0077x over previous
//
#include <hip/hip_runtime.h>
#include <math.h>

// Problem constants (from reference)
constexpr int N = 50000, E = 800000, F = 512, P = 128, G = 256, H = 256, T = 24;
// Capacity caps (expected: ~16 edges->target, ~290 2-hop edges, ~300 nodes)
constexpr int CAPA = 4096, CAPB = 32768, CAPP = 2048, CAPH = 512;

// Workspace layout (bytes), 64-aligned
constexpr size_t OFF_DEG   = 0;        // float[N]
constexpr size_t OFF_CNT   = 200704;   // int[16]: 0=cntA,1=cntB,2=cntP,3=cntH; +4: ctrl[0..7]=xcd tickets, ctrl[8]=winner
constexpr size_t OFF_COMM  = 200768;   // ull[2][256] tagged h-words (ping-pong)
constexpr size_t OFF_FH1   = 204864;   // uchar[N]
constexpr size_t OFF_FP    = 254912;   // uchar[N]
constexpr size_t ZERO_END  = 304960;   // memset [0, ZERO_END)
constexpr size_t OFF_IDXP  = 304960;   // int[N]
constexpr size_t OFF_IDXH1 = 504960;   // int[N]
constexpr size_t OFF_SRCA  = 704960;   // int[CAPA]
constexpr size_t OFF_WA    = 721344;   // float[CAPA]
constexpr size_t OFF_SRCB  = 737728;   // int[CAPB]
constexpr size_t OFF_DSTB  = 868800;   // int[CAPB]
constexpr size_t OFF_WB    = 999872;   // float[CAPB] (RAW edge gate; normalized in k_h1)
constexpr size_t OFF_LISTP = 1130944;  // int[CAPP]
constexpr size_t OFF_LISTH = 1139136;  // int[CAPH]
constexpr size_t OFF_Q     = 1141184;  // float[CAPP*G]
constexpr size_t OFF_RS    = 3238336;  // float[CAPH*G]
constexpr size_t OFF_EMB   = 3762624;  // float[2G] (only [0:256] used)
constexpr size_t OFF_XPROJ = 3764672;  // float[T*4H]

// Fast gate forms via v_exp_f32 + v_rcp_f32 (~2 ulp, fine vs 1.4e-2 threshold)
__device__ __forceinline__ float fsig_(float x) {
    return __builtin_amdgcn_rcpf(1.0f + __expf(-x));
}
__device__ __forceinline__ float ftanh_(float x) {
    return 1.0f - 2.0f * __builtin_amdgcn_rcpf(1.0f + __expf(2.0f * x));
}

// Pass 1: collect edges whose dst == target; flag 1-hop srcs. NO deg atomics
// (deg is only needed for ~320 nodes; accumulated selectively in scan2/scan3).
__global__ void k_scan1(const int* __restrict__ ei, const float* __restrict__ eg,
                        const int* __restrict__ ptgt, int* __restrict__ cnt,
                        unsigned char* __restrict__ fH1,
                        int* __restrict__ srcA, float* __restrict__ wA) {
    int target = *ptgt;
    int base = (blockIdx.x * 256 + threadIdx.x) * 4;
    if (base < E) {
        int4 d4 = *(const int4*)&ei[E + base];
        int dd0 = d4.x, dd1 = d4.y, dd2 = d4.z, dd3 = d4.w;
        #pragma unroll
        for (int j = 0; j < 4; j++) {
            int d = (j == 0) ? dd0 : (j == 1) ? dd1 : (j == 2) ? dd2 : dd3;
            if (d == target) {
                int e = base + j;
                int s = ei[e];
                int slot = atomicAdd(&cnt[0], 1);
                if (slot < CAPA) { srcA[slot] = s; wA[slot] = eg[e]; }
                fH1[s] = 1;
            }
        }
    }
    if (blockIdx.x == 0 && threadIdx.x == 0) fH1[target] = 1;
}

// Pass 2: collect edges whose dst is a needed-h1 node; flag srcs; accumulate
// deg for fH1 dsts (these edges ARE all edges into fH1 nodes; ~290 atomics).
__global__ void k_scan2(const int* __restrict__ ei, const float* __restrict__ eg,
                        const unsigned char* __restrict__ fH1, unsigned char* __restrict__ fP,
                        int* __restrict__ cnt, int* __restrict__ srcB,
                        int* __restrict__ dstB, float* __restrict__ wB,
                        float* __restrict__ deg) {
    int base = (blockIdx.x * 256 + threadIdx.x) * 4;
    if (base >= E) return;
    int4 d4 = *(const int4*)&ei[E + base];
    int dd0 = d4.x, dd1 = d4.y, dd2 = d4.z, dd3 = d4.w;
    #pragma unroll
    for (int j = 0; j < 4; j++) {
        int d = (j == 0) ? dd0 : (j == 1) ? dd1 : (j == 2) ? dd2 : dd3;
        if (fH1[d]) {
            int e = base + j;
            int s = ei[e];
            float w = eg[e];
            int slot = atomicAdd(&cnt[1], 1);
            if (slot < CAPB) { srcB[slot] = s; dstB[slot] = d; wB[slot] = w; }
            fP[s] = 1;
            atomicAdd(&deg[d], w);
        }
    }
}

// Pass 3 (fused): deg for fP-only dsts (~5K atomics) + node compaction.
__global__ void k_scan3c(const int* __restrict__ ei, const float* __restrict__ eg,
                         const unsigned char* __restrict__ fH1, const unsigned char* __restrict__ fP,
                         float* __restrict__ deg, int* __restrict__ cnt,
                         int* __restrict__ listP, int* __restrict__ listH,
                         int* __restrict__ idxP, int* __restrict__ idxH1) {
    int base = (blockIdx.x * 256 + threadIdx.x) * 4;
    if (base < E) {
        int4 d4 = *(const int4*)&ei[E + base];
        int dd0 = d4.x, dd1 = d4.y, dd2 = d4.z, dd3 = d4.w;
        #pragma unroll
        for (int j = 0; j < 4; j++) {
            int d = (j == 0) ? dd0 : (j == 1) ? dd1 : (j == 2) ? dd2 : dd3;
            if (fP[d] && !fH1[d]) atomicAdd(&deg[d], eg[base + j]);
        }
    }
    int n = blockIdx.x * 256 + threadIdx.x;
    if (n < N) {
        if (fH1[n]) {
            int sh = atomicAdd(&cnt[3], 1);
            if (sh < CAPH) listH[sh] = n;
            idxH1[n] = sh;
        }
        if (fP[n] || fH1[n]) {
            int sp = atomicAdd(&cnt[2], 1);
            if (sp < CAPP) listP[sp] = n;
            idxP[n] = sp;
        }
    }
}

// q[row] = relu((x[n]*feat_gate) @ W_proj + b_proj) @ W_g1.
// 256 blocks, round-robin rows (all blocks active), deep unroll.
__global__ void k_pq(const float* __restrict__ x, const float* __restrict__ fgate,
                     const float* __restrict__ Wproj, const float* __restrict__ bproj,
                     const float* __restrict__ Wg1, const int* __restrict__ cnt,
                     const int* __restrict__ listP, float* __restrict__ q) {
    __shared__ float xm[F];
    __shared__ float part[256];
    __shared__ float pv[P];
    int nP = min(cnt[2], CAPP);
    int tid = threadIdx.x;  // 256
    for (int row = blockIdx.x; row < nP; row += 256) {
        int n = listP[row];
        __syncthreads();  // protect LDS reuse across row iterations
        for (int i = tid; i < F; i += 256) xm[i] = x[(size_t)n * F + i] * fgate[i];
        __syncthreads();
        int col = tid & 127, kh = tid >> 7;
        const float* wp = Wproj + (size_t)(kh * 256) * P + col;
        const float* xh = xm + kh * 256;
        float acc = 0.0f;
        #pragma unroll 16
        for (int k = 0; k < 256; k++) acc += xh[k] * wp[(size_t)k * P];
        part[tid] = acc;
        __syncthreads();
        if (tid < P) pv[tid] = fmaxf(part[tid] + part[tid + 128] + bproj[tid], 0.0f);
        __syncthreads();
        float a = 0.0f;
        #pragma unroll 16
        for (int k = 0; k < P; k++) a += pv[k] * Wg1[k * G + tid];
        q[(size_t)row * G + tid] = a;
    }
}

// h1 for 1-hop-set nodes, then r = h1 @ W_g2. Edge list staged through LDS,
// with src-degree normalization applied at staging time (deg complete now).
__global__ void k_h1(const int* __restrict__ ptgt, const float* __restrict__ deg,
                     const int* __restrict__ cnt, const int* __restrict__ listH,
                     const int* __restrict__ idxP, const int* __restrict__ srcB,
                     const int* __restrict__ dstB, const float* __restrict__ wB,
                     const float* __restrict__ q, const float* __restrict__ bg1,
                     const float* __restrict__ Wg2,
                     float* __restrict__ rs, float* __restrict__ emb) {
    __shared__ float h1row[G];
    __shared__ int ldst[512];
    __shared__ int lsrc[512];
    __shared__ float lw[512];
    int b = blockIdx.x;
    int nH = min(cnt[3], CAPH);
    if (b >= nH) return;
    int n = listH[b];
    int target = *ptgt;
    int g = threadIdx.x;  // 256 threads
    float dn = rsqrtf(deg[n] + 1.0f);
    float acc = bg1[g] + q[(size_t)idxP[n] * G + g] * dn * dn;
    int nB = min(cnt[1], CAPB);
    for (int base = 0; base < nB; base += 512) {
        int m = min(512, nB - base);
        __syncthreads();
        for (int i = g; i < m; i += 256) {
            int s2 = srcB[base + i];
            ldst[i] = dstB[base + i];
            lsrc[i] = s2;
            lw[i] = wB[base + i] * rsqrtf(deg[s2] + 1.0f);
        }
        __syncthreads();
        for (int e = 0; e < m; e++) {
            if (ldst[e] == n)
                acc += lw[e] * dn * q[(size_t)idxP[lsrc[e]] * G + g];
        }
    }
    float hv = fmaxf(acc, 0.0f);
    h1row[g] = hv;
    if (n == target) emb[g] = hv;
    __syncthreads();
    float r = 0.0f;
    #pragma unroll 8
    for (int k = 0; k < G; k++) r += h1row[k] * Wg2[k * G + g];
    rs[(size_t)b * G + g] = r;
}

// xproj[t][j] = seq[t] @ W_ih[:,j] + b_ih[j] + b_hh[j]; seq built in-LDS from
// cached + emb (h1 target) + h2 target (recomputed redundantly per block).
// Separate dispatch (R11 fused it into k_lstm and the Wih fetch landed on the
// winner's critical path: k_lstm 79->112us. Un-fused, it pipelines ahead.)
__global__ void k_xproj(const float* __restrict__ cached, const float* __restrict__ emb,
                        const int* __restrict__ ptgt, const int* __restrict__ pepos,
                        const float* __restrict__ deg, const int* __restrict__ cnt,
                        const int* __restrict__ idxH1, const int* __restrict__ srcA,
                        const float* __restrict__ wA, const float* __restrict__ rs,
                        const float* __restrict__ bg2,
                        const float* __restrict__ Wih, const float* __restrict__ bih,
                        const float* __restrict__ bhh, float* __restrict__ xproj) {
    __shared__ float s[T][2 * G];  // 48 KB
    int tid = threadIdx.x;
    int epos = *pepos;
    for (int i = tid; i < T * 2 * G; i += 256) {
        int t = i >> 9, k = i & 511;
        s[t][k] = (t == epos && k < G) ? emb[k] : cached[i];
    }
    // h2[target] (redundant per block, ~16 edges)
    int target = *ptgt;
    float dt = rsqrtf(deg[target] + 1.0f);
    float h2v = 0.0f;
    if (tid < G) {
        int it = idxH1[target];
        h2v = bg2[tid] + rs[(size_t)it * G + tid] * dt * dt;
        int nA = min(cnt[0], CAPA);
        for (int e = 0; e < nA; e++) {
            int sn = srcA[e];
            h2v += rsqrtf(deg[sn] + 1.0f) * wA[e] * dt * rs[(size_t)idxH1[sn] * G + tid];
        }
    }
    __syncthreads();
    if (tid < G) s[epos][G + tid] = fmaxf(h2v, 0.0f);
    __syncthreads();
    int col = blockIdx.x * 32 + (tid & 31);
    int tg = tid >> 5;  // 0..7
    float base = bih[col] + bhh[col];
    float acc[3];
    #pragma unroll
    for (int i = 0; i < 3; i++) acc[i] = base;
    #pragma unroll 16
    for (int k = 0; k < 2 * G; k++) {
        float wv = Wih[k * 4 * H + col];
        #pragma unroll
        for (int i = 0; i < 3; i++) acc[i] += s[tg + i * 8][k] * wv;
    }
    #pragma unroll
    for (int i = 0; i < 3; i++) xproj[(tg + i * 8) * 4 * H + col] = acc[i];
}

// LSTM over 4 cooperating WGs x 256 threads on ONE XCD (ticket/crown claim).
// Thread owns gate column (tid>>6)*H + role*64 + (tid&63); its 256-element W_hh
// column lives in 16 named fv16 register vectors. Exchange = R8's proven tagged
// agent atomics + s_sleep backoff. Five mechanisms (sc1 tagged / volatile /
// single-poller / sc0-only [hang] / nt) all bracket the cross-CU store->load
// visibility at ~2.7-2.9us/step: architectural floor for this structure.
typedef float fv16 __attribute__((ext_vector_type(16)));

#define LDE(J,Eidx) wv##J[Eidx] = Whh[(size_t)((J) * 16 + (Eidx)) * 1024 + col];
#define LDV(J) LDE(J,0) LDE(J,1) LDE(J,2) LDE(J,3) LDE(J,4) LDE(J,5) LDE(J,6) LDE(J,7) \
               LDE(J,8) LDE(J,9) LDE(J,10) LDE(J,11) LDE(J,12) LDE(J,13) LDE(J,14) LDE(J,15)

#define DOT4(J,Q,ACC) { float4 h4 = hb4[(J) * 4 + (Q)]; \
    ACC += h4.x * wv##J[4*(Q)] + h4.y * wv##J[4*(Q)+1] \
         + h4.z * wv##J[4*(Q)+2] + h4.w * wv##J[4*(Q)+3]; }
#define DOTV(J) DOT4(J,0,a0) DOT4(J,1,a1) DOT4(J,2,a2) DOT4(J,3,a3)

__global__ __launch_bounds__(256, 1) void k_lstm(
        const float* __restrict__ Whh, const float* __restrict__ xproj,
        unsigned long long* __restrict__ comm, int* __restrict__ ctrl,
        const float* __restrict__ Watt, const float* __restrict__ batt,
        const float* __restrict__ Wp1, const float* __restrict__ bp1,
        const float* __restrict__ Wp2, const float* __restrict__ bp2,
        float* __restrict__ out) {
    __shared__ __align__(16) float hbuf[H];   // 1 KB
    __shared__ float glds[4 * 64];            // gate exchange
    __shared__ float rnn_lds[T][H];           // 24 KB (role-0 tail)
    __shared__ float sc[T];
    __shared__ float attw[T];
    __shared__ float ctx_l[H];
    __shared__ float watt_l[H];
    __shared__ float part[256];
    __shared__ float hid_l[64];
    __shared__ float wp2_l[64];
    __shared__ int role_s;

    int tid = threadIdx.x;     // 0..255

    // ---- same-XCD role claiming ----
    if (tid == 0) {
        int xcd;
        asm volatile("s_getreg_b32 %0, hwreg(HW_REG_XCC_ID)" : "=s"(xcd));
        xcd &= 7;
        int role = -1;
        int ticket = __hip_atomic_fetch_add(&ctrl[xcd], 1, __ATOMIC_RELAXED,
                                            __HIP_MEMORY_SCOPE_AGENT);
        if (ticket < 4) {
            if (ticket == 3) {  // 4th claimant on this XCD: try to crown it
                int expected = 0;
                __hip_atomic_compare_exchange_strong(&ctrl[8], &expected, xcd + 1,
                        __ATOMIC_RELAXED, __ATOMIC_RELAXED, __HIP_MEMORY_SCOPE_AGENT);
            }
            int wnr;
            do {
                wnr = __hip_atomic_load(&ctrl[8], __ATOMIC_RELAXED, __HIP_MEMORY_SCOPE_AGENT);
                __builtin_amdgcn_s_sleep(1);
            } while (wnr == 0);
            if (wnr == xcd + 1) role = ticket;
        }
        role_s = role;
    }
    __syncthreads();
    int w = role_s;
    if (w < 0) return;
    int l = tid & 63;                       // local channel
    int col = (tid >> 6) * H + w * 64 + l;  // global gate column

    // Preload this thread's W_hh column into 256 register lanes (coalesced).
    fv16 wv0, wv1, wv2, wv3, wv4, wv5, wv6, wv7;
    fv16 wv8, wv9, wv10, wv11, wv12, wv13, wv14, wv15;
    LDV(0) LDV(1) LDV(2) LDV(3) LDV(4) LDV(5) LDV(6) LDV(7)
    LDV(8) LDV(9) LDV(10) LDV(11) LDV(12) LDV(13) LDV(14) LDV(15)

    // This thread's poll assignment: one foreign word (tid<192).
    int pch = tid + (tid >= w * 64 ? 64 : 0);

    const float4* hb4 = (const float4*)hbuf;
    hbuf[tid] = 0.0f;
    float cstate = 0.0f;            // live in tid < 64
    float xnext = xproj[col];       // prefetch t=0
    __syncthreads();

    for (int t = 0; t < T; t++) {
        float xt = xnext;
        if (t + 1 < T) xnext = xproj[(t + 1) * 4 * H + col];  // in flight during dot
        float a0 = 0.0f, a1 = 0.0f, a2 = 0.0f, a3 = 0.0f;
        DOTV(0) DOTV(1) DOTV(2) DOTV(3) DOTV(4) DOTV(5) DOTV(6) DOTV(7)
        DOTV(8) DOTV(9) DOTV(10) DOTV(11) DOTV(12) DOTV(13) DOTV(14) DOTV(15)
        glds[tid] = ((a0 + a1) + (a2 + a3)) + xt;
        __syncthreads();
        int s = t + 1;
        // publishers: compute own 64 channels, store (agent) FIRST, then LDS.
        if (tid < 64) {
            float gi = glds[l], gf = glds[64 + l], gg = glds[128 + l], go = glds[192 + l];
            cstate = fsig_(gf) * cstate + fsig_(gi) * ftanh_(gg);
            float hv = fsig_(go) * ftanh_(cstate);
            unsigned long long word =
                ((unsigned long long)__float_as_uint(hv) << 32) | (unsigned)s;
            __hip_atomic_store(&comm[(size_t)(s & 1) * 256 + w * 64 + l], word,
                               __ATOMIC_RELAXED, __HIP_MEMORY_SCOPE_AGENT);
            hbuf[w * 64 + l] = hv;   // own channels direct to LDS
        }
        // pollers: one thread per foreign word, agent loads + sleep backoff.
        if (tid < 192) {
            const unsigned long long* cp = &comm[(size_t)(s & 1) * 256 + pch];
            unsigned long long wd =
                __hip_atomic_load(cp, __ATOMIC_RELAXED, __HIP_MEMORY_SCOPE_AGENT);
            while ((unsigned)wd != (unsigned)s) {
                __builtin_amdgcn_s_sleep(1);
                wd = __hip_atomic_load(cp, __ATOMIC_RELAXED, __HIP_MEMORY_SCOPE_AGENT);
            }
            hbuf[pch] = __uint_as_float((unsigned)(wd >> 32));
        }
        __syncthreads();
        if (w == 0) rnn_lds[t][tid] = hbuf[tid];
    }

    if (w != 0) return;
    // ---- attention + MLP tail (role 0 only) ----
    watt_l[tid] = Watt[tid];
    if (tid < 64) wp2_l[tid] = Wp2[tid];
    __syncthreads();
    if (tid < T) {
        float sv = 0.0f;
        #pragma unroll 8
        for (int h = 0; h < H; h++) sv += rnn_lds[tid][h] * watt_l[h];
        sc[tid] = tanhf(sv + batt[0]);
    }
    __syncthreads();
    if (tid == 0) {
        float m = -1e30f;
        for (int t = 0; t < T; t++) m = fmaxf(m, sc[t]);
        float su = 0.0f;
        for (int t = 0; t < T; t++) { float e = expf(sc[t] - m); attw[t] = e; su += e; }
        float inv = 1.0f / su;
        for (int t = 0; t < T; t++) attw[t] *= inv;
    }
    __syncthreads();
    {
        float a = 0.0f;
        #pragma unroll
        for (int t = 0; t < T; t++) a += rnn_lds[t][tid] * attw[t];
        ctx_l[tid] = a;
    }
    __syncthreads();
    {
        int col2 = tid & 63, sl2 = tid >> 6;  // 4 k-slices of 64
        float a = 0.0f;
        #pragma unroll 16
        for (int kk = 0; kk < 64; kk++) {
            int k = sl2 * 64 + kk;
            a += ctx_l[k] * Wp1[k * 64 + col2];
        }
        part[tid] = a;
    }
    __syncthreads();
    if (tid < 64) {
        float a = bp1[tid] + part[tid] + part[64 + tid] + part[128 + tid] + part[192 + tid];
        hid_l[tid] = fmaxf(a, 0.0f);
    }
    __syncthreads();
    if (tid == 0) {
        float r = bp2[0];
        #pragma unroll
        for (int j = 0; j < 64; j++) r += hid_l[j] * wp2_l[j];
        out[0] = (r > 20.0f) ? r : log1pf(expf(r));
    }
}

extern "C" void kernel_launch(void* const* d_in, const int* in_sizes, int n_in,
                              void* d_out, int out_size, void* d_ws, size_t ws_size,
                              hipStream_t stream) {
    const float* x      = (const float*)d_in[0];
    const int*   ei     = (const int*)d_in[1];
    const float* fgate  = (const float*)d_in[2];
    const float* egate  = (const float*)d_in[3];
    const float* cached = (const float*)d_in[4];
    const float* Wproj  = (const float*)d_in[5];
    const float* bproj  = (const float*)d_in[6];
    const float* Wg1    = (const float*)d_in[7];
    const float* bg1    = (const float*)d_in[8];
    const float* Wg2    = (const float*)d_in[9];
    const float* bg2    = (const float*)d_in[10];
    const float* Wih    = (const float*)d_in[11];
    const float* Whh    = (const float*)d_in[12];
    const float* bih    = (const float*)d_in[13];
    const float* bhh    = (const float*)d_in[14];
    const float* Watt   = (const float*)d_in[15];
    const float* batt   = (const float*)d_in[16];
    const float* Wp1    = (const float*)d_in[17];
    const float* bp1    = (const float*)d_in[18];
    const float* Wp2    = (const float*)d_in[19];
    const float* bp2    = (const float*)d_in[20];
    const int*   ptgt   = (const int*)d_in[21];
    const int*   pepos  = (const int*)d_in[22];

    char* ws = (char*)d_ws;
    float* deg   = (float*)(ws + OFF_DEG);
    int*   cnt   = (int*)(ws + OFF_CNT);
    unsigned long long* comm = (unsigned long long*)(ws + OFF_COMM);
    unsigned char* fH1 = (unsigned char*)(ws + OFF_FH1);
    unsigned char* fP  = (unsigned char*)(ws + OFF_FP);
    int*   idxP  = (int*)(ws + OFF_IDXP);
    int*   idxH1 = (int*)(ws + OFF_IDXH1);
    int*   srcA  = (int*)(ws + OFF_SRCA);
    float* wA    = (float*)(ws + OFF_WA);
    int*   srcB  = (int*)(ws + OFF_SRCB);
    int*   dstB  = (int*)(ws + OFF_DSTB);
    float* wB    = (float*)(ws + OFF_WB);
    int*   listP = (int*)(ws + OFF_LISTP);
    int*   listH = (int*)(ws + OFF_LISTH);
    float* q     = (float*)(ws + OFF_Q);
    float* rs    = (float*)(ws + OFF_RS);
    float* emb   = (float*)(ws + OFF_EMB);
    float* xproj = (float*)(ws + OFF_XPROJ);

    hipMemsetAsync(ws, 0, ZERO_END, stream);

    int nEB = (E / 4 + 255) / 256;  // 782 blocks, int4-vectorized edge scans
    k_scan1<<<nEB, 256, 0, stream>>>(ei, egate, ptgt, cnt, fH1, srcA, wA);
    k_scan2<<<nEB, 256, 0, stream>>>(ei, egate, fH1, fP, cnt, srcB, dstB, wB, deg);
    k_scan3c<<<nEB, 256, 0, stream>>>(ei, egate, fH1, fP, deg, cnt, listP, listH, idxP, idxH1);
    k_pq<<<256, 256, 0, stream>>>(x, fgate, Wproj, bproj, Wg1, cnt, listP, q);
    k_h1<<<CAPH, 256, 0, stream>>>(ptgt, deg, cnt, listH, idxP, srcB, dstB, wB, q, bg1, Wg2, rs, emb);
    k_xproj<<<32, 256, 0, stream>>>(cached, emb, ptgt, pepos, deg, cnt, idxH1, srcA, wA, rs, bg2,
                                    Wih, bih, bhh, xproj);
    k_lstm<<<64, 256, 0, stream>>>(Whh, xproj, comm, cnt + 4, Watt, batt, Wp1, bp1, Wp2, bp2,
                                   (float*)d_out);
}

// Round 13
// 150.471 us; speedup vs baseline: 1.3580x; 1.0213x over previous
//
#include <hip/hip_runtime.h>
#include <math.h>

// Problem constants (from reference)
constexpr int N = 50000, E = 800000, F = 512, P = 128, G = 256, H = 256, T = 24;
// Capacity caps (expected: ~16 edges->target, ~290 2-hop edges, ~300 nodes)
constexpr int CAPA = 4096, CAPB = 32768, CAPP = 2048, CAPH = 512;

// Workspace layout (bytes), 64-aligned
constexpr size_t OFF_DEG   = 0;        // float[N]
constexpr size_t OFF_CNT   = 200704;   // int[16]: 0=cntA,1=cntB,2=cntP,3=cntH; +4: ctrl[0..7]=xcd tickets, ctrl[8]=winner
constexpr size_t OFF_COMM  = 200768;   // ull[2][256] tagged h-words (ping-pong)
constexpr size_t OFF_FH1   = 204864;   // uchar[N]
constexpr size_t OFF_FP    = 254912;   // uchar[N]
constexpr size_t ZERO_END  = 304960;   // memset [0, ZERO_END)
constexpr size_t OFF_IDXP  = 304960;   // int[N]
constexpr size_t OFF_IDXH1 = 504960;   // int[N]
constexpr size_t OFF_SRCA  = 704960;   // int[CAPA]
constexpr size_t OFF_WA    = 721344;   // float[CAPA]
constexpr size_t OFF_SRCB  = 737728;   // int[CAPB]
constexpr size_t OFF_DSTB  = 868800;   // int[CAPB]
constexpr size_t OFF_WB    = 999872;   // float[CAPB] (RAW edge gate; normalized in k_h1)
constexpr size_t OFF_LISTP = 1130944;  // int[CAPP]
constexpr size_t OFF_LISTH = 1139136;  // int[CAPH]
constexpr size_t OFF_Q     = 1141184;  // float[CAPP*G]
constexpr size_t OFF_RS    = 3238336;  // float[CAPH*G]
constexpr size_t OFF_EMB   = 3762624;  // float[2G] (only [0:256] used)
constexpr size_t OFF_XPROJ = 3764672;  // float[T*4H]

// Fast gate forms via v_exp_f32 + v_rcp_f32 (~2 ulp, fine vs 1.4e-2 threshold)
__device__ __forceinline__ float fsig_(float x) {
    return __builtin_amdgcn_rcpf(1.0f + __expf(-x));
}
__device__ __forceinline__ float ftanh_(float x) {
    return 1.0f - 2.0f * __builtin_amdgcn_rcpf(1.0f + __expf(2.0f * x));
}

// Pass 1: collect edges whose dst == target; flag 1-hop srcs. NO deg atomics
// (deg is only needed for ~320 nodes; accumulated selectively in scan2/scan3).
__global__ void k_scan1(const int* __restrict__ ei, const float* __restrict__ eg,
                        const int* __restrict__ ptgt, int* __restrict__ cnt,
                        unsigned char* __restrict__ fH1,
                        int* __restrict__ srcA, float* __restrict__ wA) {
    int target = *ptgt;
    int base = (blockIdx.x * 256 + threadIdx.x) * 4;
    if (base < E) {
        int4 d4 = *(const int4*)&ei[E + base];
        int dd0 = d4.x, dd1 = d4.y, dd2 = d4.z, dd3 = d4.w;
        #pragma unroll
        for (int j = 0; j < 4; j++) {
            int d = (j == 0) ? dd0 : (j == 1) ? dd1 : (j == 2) ? dd2 : dd3;
            if (d == target) {
                int e = base + j;
                int s = ei[e];
                int slot = atomicAdd(&cnt[0], 1);
                if (slot < CAPA) { srcA[slot] = s; wA[slot] = eg[e]; }
                fH1[s] = 1;
            }
        }
    }
    if (blockIdx.x == 0 && threadIdx.x == 0) fH1[target] = 1;
}

// Pass 2: collect edges whose dst is a needed-h1 node; flag srcs; accumulate
// deg for fH1 dsts (these edges ARE all edges into fH1 nodes; ~290 atomics).
__global__ void k_scan2(const int* __restrict__ ei, const float* __restrict__ eg,
                        const unsigned char* __restrict__ fH1, unsigned char* __restrict__ fP,
                        int* __restrict__ cnt, int* __restrict__ srcB,
                        int* __restrict__ dstB, float* __restrict__ wB,
                        float* __restrict__ deg) {
    int base = (blockIdx.x * 256 + threadIdx.x) * 4;
    if (base >= E) return;
    int4 d4 = *(const int4*)&ei[E + base];
    int dd0 = d4.x, dd1 = d4.y, dd2 = d4.z, dd3 = d4.w;
    #pragma unroll
    for (int j = 0; j < 4; j++) {
        int d = (j == 0) ? dd0 : (j == 1) ? dd1 : (j == 2) ? dd2 : dd3;
        if (fH1[d]) {
            int e = base + j;
            int s = ei[e];
            float w = eg[e];
            int slot = atomicAdd(&cnt[1], 1);
            if (slot < CAPB) { srcB[slot] = s; dstB[slot] = d; wB[slot] = w; }
            fP[s] = 1;
            atomicAdd(&deg[d], w);
        }
    }
}

// Pass 3 (fused): deg for fP-only dsts (~5K atomics) + node compaction.
__global__ void k_scan3c(const int* __restrict__ ei, const float* __restrict__ eg,
                         const unsigned char* __restrict__ fH1, const unsigned char* __restrict__ fP,
                         float* __restrict__ deg, int* __restrict__ cnt,
                         int* __restrict__ listP, int* __restrict__ listH,
                         int* __restrict__ idxP, int* __restrict__ idxH1) {
    int base = (blockIdx.x * 256 + threadIdx.x) * 4;
    if (base < E) {
        int4 d4 = *(const int4*)&ei[E + base];
        int dd0 = d4.x, dd1 = d4.y, dd2 = d4.z, dd3 = d4.w;
        #pragma unroll
        for (int j = 0; j < 4; j++) {
            int d = (j == 0) ? dd0 : (j == 1) ? dd1 : (j == 2) ? dd2 : dd3;
            if (fP[d] && !fH1[d]) atomicAdd(&deg[d], eg[base + j]);
        }
    }
    int n = blockIdx.x * 256 + threadIdx.x;
    if (n < N) {
        if (fH1[n]) {
            int sh = atomicAdd(&cnt[3], 1);
            if (sh < CAPH) listH[sh] = n;
            idxH1[n] = sh;
        }
        if (fP[n] || fH1[n]) {
            int sp = atomicAdd(&cnt[2], 1);
            if (sp < CAPP) listP[sp] = n;
            idxP[n] = sp;
        }
    }
}

// Fused: q-precompute (blocks 0..255) + xproj PRE-pass for rows t != epos
// (blocks 256..287). The pre-pass depends only on `cached`, so the cold 2MB
// W_ih fetch overlaps pq compute instead of sitting after k_h1 on the
// critical path (R12: separate k_xproj cost ~15-25us there).
__global__ void k_pq_x(const float* __restrict__ x, const float* __restrict__ fgate,
                       const float* __restrict__ Wproj, const float* __restrict__ bproj,
                       const float* __restrict__ Wg1, const int* __restrict__ cnt,
                       const int* __restrict__ listP, float* __restrict__ q,
                       const float* __restrict__ cached, const int* __restrict__ pepos,
                       const float* __restrict__ Wih, const float* __restrict__ bih,
                       const float* __restrict__ bhh, float* __restrict__ xproj) {
    __shared__ __align__(16) char smem[49152];
    int tid = threadIdx.x;  // 256
    int bid = blockIdx.x;
    if (bid < 256) {
        // ---- pq path: q[row] = relu((x[n]*fgate) @ Wproj + b) @ Wg1 ----
        float* xm   = (float*)smem;   // [F]
        float* part = xm + F;         // [256]
        float* pv   = part + 256;     // [P]
        int nP = min(cnt[2], CAPP);
        for (int row = bid; row < nP; row += 256) {
            int n = listP[row];
            __syncthreads();  // protect LDS reuse across row iterations
            for (int i = tid; i < F; i += 256) xm[i] = x[(size_t)n * F + i] * fgate[i];
            __syncthreads();
            int col = tid & 127, kh = tid >> 7;
            const float* wp = Wproj + (size_t)(kh * 256) * P + col;
            const float* xh = xm + kh * 256;
            float acc = 0.0f;
            #pragma unroll 16
            for (int k = 0; k < 256; k++) acc += xh[k] * wp[(size_t)k * P];
            part[tid] = acc;
            __syncthreads();
            if (tid < P) pv[tid] = fmaxf(part[tid] + part[tid + 128] + bproj[tid], 0.0f);
            __syncthreads();
            float a = 0.0f;
            #pragma unroll 16
            for (int k = 0; k < P; k++) a += pv[k] * Wg1[k * G + tid];
            q[(size_t)row * G + tid] = a;
        }
    } else {
        // ---- xproj pre-pass: rows t != epos, from cached only ----
        float (*s)[2 * G] = (float(*)[2 * G])smem;  // 48 KB
        int epos = *pepos;
        for (int i = tid; i < T * 2 * G; i += 256) s[i >> 9][i & 511] = cached[i];
        __syncthreads();
        int col = (bid - 256) * 32 + (tid & 31);
        int tg = tid >> 5;  // 0..7; rows tg, tg+8, tg+16
        float base = bih[col] + bhh[col];
        float a0 = base, a1 = base, a2 = base;
        #pragma unroll 16
        for (int k = 0; k < 2 * G; k++) {
            float wv = Wih[k * 4 * H + col];
            a0 += s[tg][k] * wv; a1 += s[tg + 8][k] * wv; a2 += s[tg + 16][k] * wv;
        }
        if (tg != epos)      xproj[tg * 4 * H + col] = a0;
        if (tg + 8 != epos)  xproj[(tg + 8) * 4 * H + col] = a1;
        if (tg + 16 != epos) xproj[(tg + 16) * 4 * H + col] = a2;
    }
}

// h1 for 1-hop-set nodes, then r = h1 @ W_g2. Edge list staged through LDS,
// with src-degree normalization applied at staging time (deg complete now).
__global__ void k_h1(const int* __restrict__ ptgt, const float* __restrict__ deg,
                     const int* __restrict__ cnt, const int* __restrict__ listH,
                     const int* __restrict__ idxP, const int* __restrict__ srcB,
                     const int* __restrict__ dstB, const float* __restrict__ wB,
                     const float* __restrict__ q, const float* __restrict__ bg1,
                     const float* __restrict__ Wg2,
                     float* __restrict__ rs, float* __restrict__ emb) {
    __shared__ float h1row[G];
    __shared__ int ldst[512];
    __shared__ int lsrc[512];
    __shared__ float lw[512];
    int b = blockIdx.x;
    int nH = min(cnt[3], CAPH);
    if (b >= nH) return;
    int n = listH[b];
    int target = *ptgt;
    int g = threadIdx.x;  // 256 threads
    float dn = rsqrtf(deg[n] + 1.0f);
    float acc = bg1[g] + q[(size_t)idxP[n] * G + g] * dn * dn;
    int nB = min(cnt[1], CAPB);
    for (int base = 0; base < nB; base += 512) {
        int m = min(512, nB - base);
        __syncthreads();
        for (int i = g; i < m; i += 256) {
            int s2 = srcB[base + i];
            ldst[i] = dstB[base + i];
            lsrc[i] = s2;
            lw[i] = wB[base + i] * rsqrtf(deg[s2] + 1.0f);
        }
        __syncthreads();
        for (int e = 0; e < m; e++) {
            if (ldst[e] == n)
                acc += lw[e] * dn * q[(size_t)idxP[lsrc[e]] * G + g];
        }
    }
    float hv = fmaxf(acc, 0.0f);
    h1row[g] = hv;
    if (n == target) emb[g] = hv;
    __syncthreads();
    float r = 0.0f;
    #pragma unroll 8
    for (int k = 0; k < G; k++) r += h1row[k] * Wg2[k * G + g];
    rs[(size_t)b * G + g] = r;
}

// POST-pass: only the epos row of xproj. Computes h2[target] (redundant per
// block, ~16 edges), builds seq_epos = [emb | h2], dots against W_ih (L2/L3-
// warm from the pre-pass: 64KB/block). 32 blocks x 256 threads.
__global__ void k_xpost(const float* __restrict__ emb, const int* __restrict__ ptgt,
                        const int* __restrict__ pepos, const float* __restrict__ deg,
                        const int* __restrict__ cnt, const int* __restrict__ idxH1,
                        const int* __restrict__ srcA, const float* __restrict__ wA,
                        const float* __restrict__ rs, const float* __restrict__ bg2,
                        const float* __restrict__ Wih, const float* __restrict__ bih,
                        const float* __restrict__ bhh, float* __restrict__ xproj) {
    __shared__ float se[2 * G];
    __shared__ float red[256];
    int tid = threadIdx.x;
    int target = *ptgt, epos = *pepos;
    float dt = rsqrtf(deg[target] + 1.0f);
    if (tid < G) {
        se[tid] = emb[tid];
        int it = idxH1[target];
        float h2v = bg2[tid] + rs[(size_t)it * G + tid] * dt * dt;
        int nA = min(cnt[0], CAPA);
        for (int e = 0; e < nA; e++) {
            int sn = srcA[e];
            h2v += rsqrtf(deg[sn] + 1.0f) * wA[e] * dt * rs[(size_t)idxH1[sn] * G + tid];
        }
        se[G + tid] = fmaxf(h2v, 0.0f);
    }
    __syncthreads();
    int col = blockIdx.x * 32 + (tid & 31);
    int ks = tid >> 5;  // 8 k-slices of 64
    float a = 0.0f;
    #pragma unroll 16
    for (int kk = 0; kk < 64; kk++) {
        int k = ks * 64 + kk;
        a += se[k] * Wih[k * 4 * H + col];
    }
    red[tid] = a;
    __syncthreads();
    if (tid < 32) {
        int c2 = blockIdx.x * 32 + tid;
        float s2 = bih[c2] + bhh[c2];
        #pragma unroll
        for (int j = 0; j < 8; j++) s2 += red[j * 32 + tid];
        xproj[epos * 4 * H + c2] = s2;
    }
}

// LSTM over 4 cooperating WGs x 256 threads on ONE XCD (ticket/crown claim).
// Thread owns gate column (tid>>6)*H + role*64 + (tid&63); its 256-element W_hh
// column lives in 16 named fv16 register vectors. Exchange = R8's proven tagged
// agent atomics + s_sleep backoff. Five mechanisms (sc1 tagged / volatile /
// single-poller / sc0-only [hang] / nt) all bracket the cross-CU store->load
// visibility at ~2.7-2.9us/step: architectural floor for this structure.
typedef float fv16 __attribute__((ext_vector_type(16)));

#define LDE(J,Eidx) wv##J[Eidx] = Whh[(size_t)((J) * 16 + (Eidx)) * 1024 + col];
#define LDV(J) LDE(J,0) LDE(J,1) LDE(J,2) LDE(J,3) LDE(J,4) LDE(J,5) LDE(J,6) LDE(J,7) \
               LDE(J,8) LDE(J,9) LDE(J,10) LDE(J,11) LDE(J,12) LDE(J,13) LDE(J,14) LDE(J,15)

#define DOT4(J,Q,ACC) { float4 h4 = hb4[(J) * 4 + (Q)]; \
    ACC += h4.x * wv##J[4*(Q)] + h4.y * wv##J[4*(Q)+1] \
         + h4.z * wv##J[4*(Q)+2] + h4.w * wv##J[4*(Q)+3]; }
#define DOTV(J) DOT4(J,0,a0) DOT4(J,1,a1) DOT4(J,2,a2) DOT4(J,3,a3)

__global__ __launch_bounds__(256, 1) void k_lstm(
        const float* __restrict__ Whh, const float* __restrict__ xproj,
        unsigned long long* __restrict__ comm, int* __restrict__ ctrl,
        const float* __restrict__ Watt, const float* __restrict__ batt,
        const float* __restrict__ Wp1, const float* __restrict__ bp1,
        const float* __restrict__ Wp2, const float* __restrict__ bp2,
        float* __restrict__ out) {
    __shared__ __align__(16) float hbuf[H];   // 1 KB
    __shared__ float glds[4 * 64];            // gate exchange
    __shared__ float rnn_lds[T][H];           // 24 KB (role-0 tail)
    __shared__ float sc[T];
    __shared__ float attw[T];
    __shared__ float ctx_l[H];
    __shared__ float watt_l[H];
    __shared__ float part[256];
    __shared__ float hid_l[64];
    __shared__ float wp2_l[64];
    __shared__ int role_s;

    int tid = threadIdx.x;     // 0..255

    // ---- same-XCD role claiming ----
    if (tid == 0) {
        int xcd;
        asm volatile("s_getreg_b32 %0, hwreg(HW_REG_XCC_ID)" : "=s"(xcd));
        xcd &= 7;
        int role = -1;
        int ticket = __hip_atomic_fetch_add(&ctrl[xcd], 1, __ATOMIC_RELAXED,
                                            __HIP_MEMORY_SCOPE_AGENT);
        if (ticket < 4) {
            if (ticket == 3) {  // 4th claimant on this XCD: try to crown it
                int expected = 0;
                __hip_atomic_compare_exchange_strong(&ctrl[8], &expected, xcd + 1,
                        __ATOMIC_RELAXED, __ATOMIC_RELAXED, __HIP_MEMORY_SCOPE_AGENT);
            }
            int wnr;
            do {
                wnr = __hip_atomic_load(&ctrl[8], __ATOMIC_RELAXED, __HIP_MEMORY_SCOPE_AGENT);
                __builtin_amdgcn_s_sleep(1);
            } while (wnr == 0);
            if (wnr == xcd + 1) role = ticket;
        }
        role_s = role;
    }
    __syncthreads();
    int w = role_s;
    if (w < 0) return;
    int l = tid & 63;                       // local channel
    int col = (tid >> 6) * H + w * 64 + l;  // global gate column

    // Preload this thread's W_hh column into 256 register lanes (coalesced).
    fv16 wv0, wv1, wv2, wv3, wv4, wv5, wv6, wv7;
    fv16 wv8, wv9, wv10, wv11, wv12, wv13, wv14, wv15;
    LDV(0) LDV(1) LDV(2) LDV(3) LDV(4) LDV(5) LDV(6) LDV(7)
    LDV(8) LDV(9) LDV(10) LDV(11) LDV(12) LDV(13) LDV(14) LDV(15)

    // This thread's poll assignment: one foreign word (tid<192).
    int pch = tid + (tid >= w * 64 ? 64 : 0);

    const float4* hb4 = (const float4*)hbuf;
    hbuf[tid] = 0.0f;
    float cstate = 0.0f;            // live in tid < 64
    float xnext = xproj[col];       // prefetch t=0
    __syncthreads();

    for (int t = 0; t < T; t++) {
        float xt = xnext;
        if (t + 1 < T) xnext = xproj[(t + 1) * 4 * H + col];  // in flight during dot
        float a0 = 0.0f, a1 = 0.0f, a2 = 0.0f, a3 = 0.0f;
        DOTV(0) DOTV(1) DOTV(2) DOTV(3) DOTV(4) DOTV(5) DOTV(6) DOTV(7)
        DOTV(8) DOTV(9) DOTV(10) DOTV(11) DOTV(12) DOTV(13) DOTV(14) DOTV(15)
        glds[tid] = ((a0 + a1) + (a2 + a3)) + xt;
        __syncthreads();
        int s = t + 1;
        // publishers: compute own 64 channels, store (agent) FIRST, then LDS.
        if (tid < 64) {
            float gi = glds[l], gf = glds[64 + l], gg = glds[128 + l], go = glds[192 + l];
            cstate = fsig_(gf) * cstate + fsig_(gi) * ftanh_(gg);
            float hv = fsig_(go) * ftanh_(cstate);
            unsigned long long word =
                ((unsigned long long)__float_as_uint(hv) << 32) | (unsigned)s;
            __hip_atomic_store(&comm[(size_t)(s & 1) * 256 + w * 64 + l], word,
                               __ATOMIC_RELAXED, __HIP_MEMORY_SCOPE_AGENT);
            hbuf[w * 64 + l] = hv;   // own channels direct to LDS
        }
        // pollers: one thread per foreign word, agent loads + sleep backoff.
        if (tid < 192) {
            const unsigned long long* cp = &comm[(size_t)(s & 1) * 256 + pch];
            unsigned long long wd =
                __hip_atomic_load(cp, __ATOMIC_RELAXED, __HIP_MEMORY_SCOPE_AGENT);
            while ((unsigned)wd != (unsigned)s) {
                __builtin_amdgcn_s_sleep(1);
                wd = __hip_atomic_load(cp, __ATOMIC_RELAXED, __HIP_MEMORY_SCOPE_AGENT);
            }
            hbuf[pch] = __uint_as_float((unsigned)(wd >> 32));
        }
        __syncthreads();
        if (w == 0) rnn_lds[t][tid] = hbuf[tid];
    }

    if (w != 0) return;
    // ---- attention + MLP tail (role 0 only) ----
    watt_l[tid] = Watt[tid];
    if (tid < 64) wp2_l[tid] = Wp2[tid];
    __syncthreads();
    if (tid < T) {
        float sv = 0.0f;
        #pragma unroll 8
        for (int h = 0; h < H; h++) sv += rnn_lds[tid][h] * watt_l[h];
        sc[tid] = tanhf(sv + batt[0]);
    }
    __syncthreads();
    if (tid == 0) {
        float m = -1e30f;
        for (int t = 0; t < T; t++) m = fmaxf(m, sc[t]);
        float su = 0.0f;
        for (int t = 0; t < T; t++) { float e = expf(sc[t] - m); attw[t] = e; su += e; }
        float inv = 1.0f / su;
        for (int t = 0; t < T; t++) attw[t] *= inv;
    }
    __syncthreads();
    {
        float a = 0.0f;
        #pragma unroll
        for (int t = 0; t < T; t++) a += rnn_lds[t][tid] * attw[t];
        ctx_l[tid] = a;
    }
    __syncthreads();
    {
        int col2 = tid & 63, sl2 = tid >> 6;  // 4 k-slices of 64
        float a = 0.0f;
        #pragma unroll 16
        for (int kk = 0; kk < 64; kk++) {
            int k = sl2 * 64 + kk;
            a += ctx_l[k] * Wp1[k * 64 + col2];
        }
        part[tid] = a;
    }
    __syncthreads();
    if (tid < 64) {
        float a = bp1[tid] + part[tid] + part[64 + tid] + part[128 + tid] + part[192 + tid];
        hid_l[tid] = fmaxf(a, 0.0f);
    }
    __syncthreads();
    if (tid == 0) {
        float r = bp2[0];
        #pragma unroll
        for (int j = 0; j < 64; j++) r += hid_l[j] * wp2_l[j];
        out[0] = (r > 20.0f) ? r : log1pf(expf(r));
    }
}

extern "C" void kernel_launch(void* const* d_in, const int* in_sizes, int n_in,
                              void* d_out, int out_size, void* d_ws, size_t ws_size,
                              hipStream_t stream) {
    const float* x      = (const float*)d_in[0];
    const int*   ei     = (const int*)d_in[1];
    const float* fgate  = (const float*)d_in[2];
    const float* egate  = (const float*)d_in[3];
    const float* cached = (const float*)d_in[4];
    const float* Wproj  = (const float*)d_in[5];
    const float* bproj  = (const float*)d_in[6];
    const float* Wg1    = (const float*)d_in[7];
    const float* bg1    = (const float*)d_in[8];
    const float* Wg2    = (const float*)d_in[9];
    const float* bg2    = (const float*)d_in[10];
    const float* Wih    = (const float*)d_in[11];
    const float* Whh    = (const float*)d_in[12];
    const float* bih    = (const float*)d_in[13];
    const float* bhh    = (const float*)d_in[14];
    const float* Watt   = (const float*)d_in[15];
    const float* batt   = (const float*)d_in[16];
    const float* Wp1    = (const float*)d_in[17];
    const float* bp1    = (const float*)d_in[18];
    const float* Wp2    = (const float*)d_in[19];
    const float* bp2    = (const float*)d_in[20];
    const int*   ptgt   = (const int*)d_in[21];
    const int*   pepos  = (const int*)d_in[22];

    char* ws = (char*)d_ws;
    float* deg   = (float*)(ws + OFF_DEG);
    int*   cnt   = (int*)(ws + OFF_CNT);
    unsigned long long* comm = (unsigned long long*)(ws + OFF_COMM);
    unsigned char* fH1 = (unsigned char*)(ws + OFF_FH1);
    unsigned char* fP  = (unsigned char*)(ws + OFF_FP);
    int*   idxP  = (int*)(ws + OFF_IDXP);
    int*   idxH1 = (int*)(ws + OFF_IDXH1);
    int*   srcA  = (int*)(ws + OFF_SRCA);
    float* wA    = (float*)(ws + OFF_WA);
    int*   srcB  = (int*)(ws + OFF_SRCB);
    int*   dstB  = (int*)(ws + OFF_DSTB);
    float* wB    = (float*)(ws + OFF_WB);
    int*   listP = (int*)(ws + OFF_LISTP);
    int*   listH = (int*)(ws + OFF_LISTH);
    float* q     = (float*)(ws + OFF_Q);
    float* rs    = (float*)(ws + OFF_RS);
    float* emb   = (float*)(ws + OFF_EMB);
    float* xproj = (float*)(ws + OFF_XPROJ);

    hipMemsetAsync(ws, 0, ZERO_END, stream);

    int nEB = (E / 4 + 255) / 256;  // 782 blocks, int4-vectorized edge scans
    k_scan1<<<nEB, 256, 0, stream>>>(ei, egate, ptgt, cnt, fH1, srcA, wA);
    k_scan2<<<nEB, 256, 0, stream>>>(ei, egate, fH1, fP, cnt, srcB, dstB, wB, deg);
    k_scan3c<<<nEB, 256, 0, stream>>>(ei, egate, fH1, fP, deg, cnt, listP, listH, idxP, idxH1);
    k_pq_x<<<288, 256, 0, stream>>>(x, fgate, Wproj, bproj, Wg1, cnt, listP, q,
                                    cached, pepos, Wih, bih, bhh, xproj);
    k_h1<<<CAPH, 256, 0, stream>>>(ptgt, deg, cnt, listH, idxP, srcB, dstB, wB, q, bg1, Wg2, rs, emb);
    k_xpost<<<32, 256, 0, stream>>>(emb, ptgt, pepos, deg, cnt, idxH1, srcA, wA, rs, bg2,
                                    Wih, bih, bhh, xproj);
    k_lstm<<<64, 256, 0, stream>>>(Whh, xproj, comm, cnt + 4, Watt, batt, Wp1, bp1, Wp2, bp2,
                                   (float*)d_out);
}

// Round 14
// 149.302 us; speedup vs baseline: 1.3686x; 1.0078x over previous
//
#include <hip/hip_runtime.h>
#include <math.h>

// Problem constants (from reference)
constexpr int N = 50000, E = 800000, F = 512, P = 128, G = 256, H = 256, T = 24;
// Capacity caps (expected: ~16 edges->target, ~290 2-hop edges, ~300 nodes)
constexpr int CAPA = 4096, CAPB = 32768, CAPP = 2048, CAPH = 512;

// Workspace layout (bytes), 64-aligned
constexpr size_t OFF_DEG   = 0;        // float[N]
constexpr size_t OFF_CNT   = 200704;   // int[16]: 0=cntA,1=cntB,2=cntP,3=cntH; +4: ctrl[0..7]=xcd tickets, ctrl[8]=winner
constexpr size_t OFF_COMM  = 200768;   // ull[2][256] tagged h-words (ping-pong)
constexpr size_t OFF_FH1   = 204864;   // uchar[N]
constexpr size_t OFF_FP    = 254912;   // uchar[N]
constexpr size_t ZERO_END  = 304960;   // memset [0, ZERO_END)
constexpr size_t OFF_IDXP  = 304960;   // int[N]
constexpr size_t OFF_IDXH1 = 504960;   // int[N]
constexpr size_t OFF_SRCA  = 704960;   // int[CAPA]
constexpr size_t OFF_WA    = 721344;   // float[CAPA]
constexpr size_t OFF_SRCB  = 737728;   // int[CAPB]
constexpr size_t OFF_DSTB  = 868800;   // int[CAPB]
constexpr size_t OFF_WB    = 999872;   // float[CAPB] (RAW edge gate; normalized in k_h1)
constexpr size_t OFF_LISTP = 1130944;  // int[CAPP]
constexpr size_t OFF_LISTH = 1139136;  // int[CAPH]
constexpr size_t OFF_Q     = 1141184;  // float[CAPP*G]
constexpr size_t OFF_RS    = 3238336;  // float[CAPH*G]
constexpr size_t OFF_EMB   = 3762624;  // float[2G] (only [0:256] used)
constexpr size_t OFF_XPROJ = 3764672;  // float[T*4H]

// Fast gate forms via v_exp_f32 + v_rcp_f32 (~2 ulp, fine vs 1.4e-2 threshold)
__device__ __forceinline__ float fsig_(float x) {
    return __builtin_amdgcn_rcpf(1.0f + __expf(-x));
}
__device__ __forceinline__ float ftanh_(float x) {
    return 1.0f - 2.0f * __builtin_amdgcn_rcpf(1.0f + __expf(2.0f * x));
}

// Pass 1: collect edges whose dst == target; flag 1-hop srcs. NO deg atomics.
// Also: WARM W_hh INTO L3 (one coalesced 1MB float4 sweep, asm sink vs DCE) so
// k_lstm's strided 256-deep per-thread preload hits Infinity Cache, not HBM.
__global__ void k_scan1(const int* __restrict__ ei, const float* __restrict__ eg,
                        const int* __restrict__ ptgt, int* __restrict__ cnt,
                        unsigned char* __restrict__ fH1,
                        int* __restrict__ srcA, float* __restrict__ wA,
                        const float* __restrict__ Whh) {
    int gid = blockIdx.x * 256 + threadIdx.x;
    if (gid < 65536) {  // 65536 float4 = 1MB = all of W_hh
        float4 wv = *(const float4*)&Whh[(size_t)gid * 4];
        asm volatile("" :: "v"(wv.x), "v"(wv.y), "v"(wv.z), "v"(wv.w));
    }
    int target = *ptgt;
    int base = gid * 4;
    if (base < E) {
        int4 d4 = *(const int4*)&ei[E + base];
        int dd0 = d4.x, dd1 = d4.y, dd2 = d4.z, dd3 = d4.w;
        #pragma unroll
        for (int j = 0; j < 4; j++) {
            int d = (j == 0) ? dd0 : (j == 1) ? dd1 : (j == 2) ? dd2 : dd3;
            if (d == target) {
                int e = base + j;
                int s = ei[e];
                int slot = atomicAdd(&cnt[0], 1);
                if (slot < CAPA) { srcA[slot] = s; wA[slot] = eg[e]; }
                fH1[s] = 1;
            }
        }
    }
    if (gid == 0) fH1[target] = 1;
}

// Pass 2: collect edges whose dst is a needed-h1 node; flag srcs; accumulate
// deg for fH1 dsts (these edges ARE all edges into fH1 nodes; ~290 atomics).
__global__ void k_scan2(const int* __restrict__ ei, const float* __restrict__ eg,
                        const unsigned char* __restrict__ fH1, unsigned char* __restrict__ fP,
                        int* __restrict__ cnt, int* __restrict__ srcB,
                        int* __restrict__ dstB, float* __restrict__ wB,
                        float* __restrict__ deg) {
    int base = (blockIdx.x * 256 + threadIdx.x) * 4;
    if (base >= E) return;
    int4 d4 = *(const int4*)&ei[E + base];
    int dd0 = d4.x, dd1 = d4.y, dd2 = d4.z, dd3 = d4.w;
    #pragma unroll
    for (int j = 0; j < 4; j++) {
        int d = (j == 0) ? dd0 : (j == 1) ? dd1 : (j == 2) ? dd2 : dd3;
        if (fH1[d]) {
            int e = base + j;
            int s = ei[e];
            float w = eg[e];
            int slot = atomicAdd(&cnt[1], 1);
            if (slot < CAPB) { srcB[slot] = s; dstB[slot] = d; wB[slot] = w; }
            fP[s] = 1;
            atomicAdd(&deg[d], w);
        }
    }
}

// Pass 3 (fused): deg for fP-only dsts (~5K atomics) + node compaction.
__global__ void k_scan3c(const int* __restrict__ ei, const float* __restrict__ eg,
                         const unsigned char* __restrict__ fH1, const unsigned char* __restrict__ fP,
                         float* __restrict__ deg, int* __restrict__ cnt,
                         int* __restrict__ listP, int* __restrict__ listH,
                         int* __restrict__ idxP, int* __restrict__ idxH1) {
    int base = (blockIdx.x * 256 + threadIdx.x) * 4;
    if (base < E) {
        int4 d4 = *(const int4*)&ei[E + base];
        int dd0 = d4.x, dd1 = d4.y, dd2 = d4.z, dd3 = d4.w;
        #pragma unroll
        for (int j = 0; j < 4; j++) {
            int d = (j == 0) ? dd0 : (j == 1) ? dd1 : (j == 2) ? dd2 : dd3;
            if (fP[d] && !fH1[d]) atomicAdd(&deg[d], eg[base + j]);
        }
    }
    int n = blockIdx.x * 256 + threadIdx.x;
    if (n < N) {
        if (fH1[n]) {
            int sh = atomicAdd(&cnt[3], 1);
            if (sh < CAPH) listH[sh] = n;
            idxH1[n] = sh;
        }
        if (fP[n] || fH1[n]) {
            int sp = atomicAdd(&cnt[2], 1);
            if (sp < CAPP) listP[sp] = n;
            idxP[n] = sp;
        }
    }
}

// Fused: q-precompute (blocks 0..255) + xproj PRE-pass for rows t != epos
// (blocks 256..287). The pre-pass depends only on `cached`, so the cold 2MB
// W_ih fetch overlaps pq compute instead of sitting after k_h1 on the
// critical path.
__global__ void k_pq_x(const float* __restrict__ x, const float* __restrict__ fgate,
                       const float* __restrict__ Wproj, const float* __restrict__ bproj,
                       const float* __restrict__ Wg1, const int* __restrict__ cnt,
                       const int* __restrict__ listP, float* __restrict__ q,
                       const float* __restrict__ cached, const int* __restrict__ pepos,
                       const float* __restrict__ Wih, const float* __restrict__ bih,
                       const float* __restrict__ bhh, float* __restrict__ xproj) {
    __shared__ __align__(16) char smem[49152];
    int tid = threadIdx.x;  // 256
    int bid = blockIdx.x;
    if (bid < 256) {
        // ---- pq path: q[row] = relu((x[n]*fgate) @ Wproj + b) @ Wg1 ----
        float* xm   = (float*)smem;   // [F]
        float* part = xm + F;         // [256]
        float* pv   = part + 256;     // [P]
        int nP = min(cnt[2], CAPP);
        for (int row = bid; row < nP; row += 256) {
            int n = listP[row];
            __syncthreads();  // protect LDS reuse across row iterations
            for (int i = tid; i < F; i += 256) xm[i] = x[(size_t)n * F + i] * fgate[i];
            __syncthreads();
            int col = tid & 127, kh = tid >> 7;
            const float* wp = Wproj + (size_t)(kh * 256) * P + col;
            const float* xh = xm + kh * 256;
            float acc = 0.0f;
            #pragma unroll 16
            for (int k = 0; k < 256; k++) acc += xh[k] * wp[(size_t)k * P];
            part[tid] = acc;
            __syncthreads();
            if (tid < P) pv[tid] = fmaxf(part[tid] + part[tid + 128] + bproj[tid], 0.0f);
            __syncthreads();
            float a = 0.0f;
            #pragma unroll 16
            for (int k = 0; k < P; k++) a += pv[k] * Wg1[k * G + tid];
            q[(size_t)row * G + tid] = a;
        }
    } else {
        // ---- xproj pre-pass: rows t != epos, from cached only ----
        float (*s)[2 * G] = (float(*)[2 * G])smem;  // 48 KB
        int epos = *pepos;
        for (int i = tid; i < T * 2 * G; i += 256) s[i >> 9][i & 511] = cached[i];
        __syncthreads();
        int col = (bid - 256) * 32 + (tid & 31);
        int tg = tid >> 5;  // 0..7; rows tg, tg+8, tg+16
        float base = bih[col] + bhh[col];
        float a0 = base, a1 = base, a2 = base;
        #pragma unroll 16
        for (int k = 0; k < 2 * G; k++) {
            float wv = Wih[k * 4 * H + col];
            a0 += s[tg][k] * wv; a1 += s[tg + 8][k] * wv; a2 += s[tg + 16][k] * wv;
        }
        if (tg != epos)      xproj[tg * 4 * H + col] = a0;
        if (tg + 8 != epos)  xproj[(tg + 8) * 4 * H + col] = a1;
        if (tg + 16 != epos) xproj[(tg + 16) * 4 * H + col] = a2;
    }
}

// h1 for 1-hop-set nodes, then r = h1 @ W_g2. Edge list staged through LDS,
// with src-degree normalization applied at staging time (deg complete now).
__global__ void k_h1(const int* __restrict__ ptgt, const float* __restrict__ deg,
                     const int* __restrict__ cnt, const int* __restrict__ listH,
                     const int* __restrict__ idxP, const int* __restrict__ srcB,
                     const int* __restrict__ dstB, const float* __restrict__ wB,
                     const float* __restrict__ q, const float* __restrict__ bg1,
                     const float* __restrict__ Wg2,
                     float* __restrict__ rs, float* __restrict__ emb) {
    __shared__ float h1row[G];
    __shared__ int ldst[512];
    __shared__ int lsrc[512];
    __shared__ float lw[512];
    int b = blockIdx.x;
    int nH = min(cnt[3], CAPH);
    if (b >= nH) return;
    int n = listH[b];
    int target = *ptgt;
    int g = threadIdx.x;  // 256 threads
    float dn = rsqrtf(deg[n] + 1.0f);
    float acc = bg1[g] + q[(size_t)idxP[n] * G + g] * dn * dn;
    int nB = min(cnt[1], CAPB);
    for (int base = 0; base < nB; base += 512) {
        int m = min(512, nB - base);
        __syncthreads();
        for (int i = g; i < m; i += 256) {
            int s2 = srcB[base + i];
            ldst[i] = dstB[base + i];
            lsrc[i] = s2;
            lw[i] = wB[base + i] * rsqrtf(deg[s2] + 1.0f);
        }
        __syncthreads();
        for (int e = 0; e < m; e++) {
            if (ldst[e] == n)
                acc += lw[e] * dn * q[(size_t)idxP[lsrc[e]] * G + g];
        }
    }
    float hv = fmaxf(acc, 0.0f);
    h1row[g] = hv;
    if (n == target) emb[g] = hv;
    __syncthreads();
    float r = 0.0f;
    #pragma unroll 8
    for (int k = 0; k < G; k++) r += h1row[k] * Wg2[k * G + g];
    rs[(size_t)b * G + g] = r;
}

// POST-pass: only the epos row of xproj. Computes h2[target] (redundant per
// block, ~16 edges), builds seq_epos = [emb | h2], dots against W_ih (L2/L3-
// warm from the pre-pass: 64KB/block). 32 blocks x 256 threads.
__global__ void k_xpost(const float* __restrict__ emb, const int* __restrict__ ptgt,
                        const int* __restrict__ pepos, const float* __restrict__ deg,
                        const int* __restrict__ cnt, const int* __restrict__ idxH1,
                        const int* __restrict__ srcA, const float* __restrict__ wA,
                        const float* __restrict__ rs, const float* __restrict__ bg2,
                        const float* __restrict__ Wih, const float* __restrict__ bih,
                        const float* __restrict__ bhh, float* __restrict__ xproj) {
    __shared__ float se[2 * G];
    __shared__ float red[256];
    int tid = threadIdx.x;
    int target = *ptgt, epos = *pepos;
    float dt = rsqrtf(deg[target] + 1.0f);
    if (tid < G) {
        se[tid] = emb[tid];
        int it = idxH1[target];
        float h2v = bg2[tid] + rs[(size_t)it * G + tid] * dt * dt;
        int nA = min(cnt[0], CAPA);
        for (int e = 0; e < nA; e++) {
            int sn = srcA[e];
            h2v += rsqrtf(deg[sn] + 1.0f) * wA[e] * dt * rs[(size_t)idxH1[sn] * G + tid];
        }
        se[G + tid] = fmaxf(h2v, 0.0f);
    }
    __syncthreads();
    int col = blockIdx.x * 32 + (tid & 31);
    int ks = tid >> 5;  // 8 k-slices of 64
    float a = 0.0f;
    #pragma unroll 16
    for (int kk = 0; kk < 64; kk++) {
        int k = ks * 64 + kk;
        a += se[k] * Wih[k * 4 * H + col];
    }
    red[tid] = a;
    __syncthreads();
    if (tid < 32) {
        int c2 = blockIdx.x * 32 + tid;
        float s2 = bih[c2] + bhh[c2];
        #pragma unroll
        for (int j = 0; j < 8; j++) s2 += red[j * 32 + tid];
        xproj[epos * 4 * H + c2] = s2;
    }
}

// LSTM over 4 cooperating WGs x 256 threads on ONE XCD (ticket/crown claim;
// 32 launched WGs — pigeonhole over 8 XCDs still guarantees a winner with 4).
// Thread owns gate column (tid>>6)*H + role*64 + (tid&63); its 256-element W_hh
// column lives in 16 named fv16 register vectors (preload now L3-warm via
// k_scan1's sweep). Exchange = proven tagged agent atomics + s_sleep backoff
// (five mechanisms bracket cross-CU visibility at ~2.7-2.9us/step).
typedef float fv16 __attribute__((ext_vector_type(16)));

#define LDE(J,Eidx) wv##J[Eidx] = Whh[(size_t)((J) * 16 + (Eidx)) * 1024 + col];
#define LDV(J) LDE(J,0) LDE(J,1) LDE(J,2) LDE(J,3) LDE(J,4) LDE(J,5) LDE(J,6) LDE(J,7) \
               LDE(J,8) LDE(J,9) LDE(J,10) LDE(J,11) LDE(J,12) LDE(J,13) LDE(J,14) LDE(J,15)

#define DOT4(J,Q,ACC) { float4 h4 = hb4[(J) * 4 + (Q)]; \
    ACC += h4.x * wv##J[4*(Q)] + h4.y * wv##J[4*(Q)+1] \
         + h4.z * wv##J[4*(Q)+2] + h4.w * wv##J[4*(Q)+3]; }
#define DOTV(J) DOT4(J,0,a0) DOT4(J,1,a1) DOT4(J,2,a2) DOT4(J,3,a3)

__global__ __launch_bounds__(256, 1) void k_lstm(
        const float* __restrict__ Whh, const float* __restrict__ xproj,
        unsigned long long* __restrict__ comm, int* __restrict__ ctrl,
        const float* __restrict__ Watt, const float* __restrict__ batt,
        const float* __restrict__ Wp1, const float* __restrict__ bp1,
        const float* __restrict__ Wp2, const float* __restrict__ bp2,
        float* __restrict__ out) {
    __shared__ __align__(16) float hbuf[H];   // 1 KB
    __shared__ float glds[4 * 64];            // gate exchange
    __shared__ float rnn_lds[T][H];           // 24 KB (role-0 tail)
    __shared__ float sc[T];
    __shared__ float attw[T];
    __shared__ float ctx_l[H];
    __shared__ float watt_l[H];
    __shared__ float part[256];
    __shared__ float hid_l[64];
    __shared__ float wp2_l[64];
    __shared__ int role_s;

    int tid = threadIdx.x;     // 0..255

    // ---- same-XCD role claiming ----
    if (tid == 0) {
        int xcd;
        asm volatile("s_getreg_b32 %0, hwreg(HW_REG_XCC_ID)" : "=s"(xcd));
        xcd &= 7;
        int role = -1;
        int ticket = __hip_atomic_fetch_add(&ctrl[xcd], 1, __ATOMIC_RELAXED,
                                            __HIP_MEMORY_SCOPE_AGENT);
        if (ticket < 4) {
            if (ticket == 3) {  // 4th claimant on this XCD: try to crown it
                int expected = 0;
                __hip_atomic_compare_exchange_strong(&ctrl[8], &expected, xcd + 1,
                        __ATOMIC_RELAXED, __ATOMIC_RELAXED, __HIP_MEMORY_SCOPE_AGENT);
            }
            int wnr;
            do {
                wnr = __hip_atomic_load(&ctrl[8], __ATOMIC_RELAXED, __HIP_MEMORY_SCOPE_AGENT);
                __builtin_amdgcn_s_sleep(1);
            } while (wnr == 0);
            if (wnr == xcd + 1) role = ticket;
        }
        role_s = role;
    }
    __syncthreads();
    int w = role_s;
    if (w < 0) return;
    int l = tid & 63;                       // local channel
    int col = (tid >> 6) * H + w * 64 + l;  // global gate column

    // Preload this thread's W_hh column into 256 register lanes (L3-warm).
    fv16 wv0, wv1, wv2, wv3, wv4, wv5, wv6, wv7;
    fv16 wv8, wv9, wv10, wv11, wv12, wv13, wv14, wv15;
    LDV(0) LDV(1) LDV(2) LDV(3) LDV(4) LDV(5) LDV(6) LDV(7)
    LDV(8) LDV(9) LDV(10) LDV(11) LDV(12) LDV(13) LDV(14) LDV(15)

    // This thread's poll assignment: one foreign word (tid<192).
    int pch = tid + (tid >= w * 64 ? 64 : 0);

    const float4* hb4 = (const float4*)hbuf;
    hbuf[tid] = 0.0f;
    float cstate = 0.0f;            // live in tid < 64
    float xnext = xproj[col];       // prefetch t=0
    __syncthreads();

    for (int t = 0; t < T; t++) {
        float xt = xnext;
        if (t + 1 < T) xnext = xproj[(t + 1) * 4 * H + col];  // in flight during dot
        float a0 = 0.0f, a1 = 0.0f, a2 = 0.0f, a3 = 0.0f;
        DOTV(0) DOTV(1) DOTV(2) DOTV(3) DOTV(4) DOTV(5) DOTV(6) DOTV(7)
        DOTV(8) DOTV(9) DOTV(10) DOTV(11) DOTV(12) DOTV(13) DOTV(14) DOTV(15)
        glds[tid] = ((a0 + a1) + (a2 + a3)) + xt;
        __syncthreads();
        int s = t + 1;
        // publishers: compute own 64 channels, store (agent) FIRST, then LDS.
        if (tid < 64) {
            float gi = glds[l], gf = glds[64 + l], gg = glds[128 + l], go = glds[192 + l];
            cstate = fsig_(gf) * cstate + fsig_(gi) * ftanh_(gg);
            float hv = fsig_(go) * ftanh_(cstate);
            unsigned long long word =
                ((unsigned long long)__float_as_uint(hv) << 32) | (unsigned)s;
            __hip_atomic_store(&comm[(size_t)(s & 1) * 256 + w * 64 + l], word,
                               __ATOMIC_RELAXED, __HIP_MEMORY_SCOPE_AGENT);
            hbuf[w * 64 + l] = hv;   // own channels direct to LDS
        }
        // pollers: one thread per foreign word, agent loads + sleep backoff.
        if (tid < 192) {
            const unsigned long long* cp = &comm[(size_t)(s & 1) * 256 + pch];
            unsigned long long wd =
                __hip_atomic_load(cp, __ATOMIC_RELAXED, __HIP_MEMORY_SCOPE_AGENT);
            while ((unsigned)wd != (unsigned)s) {
                __builtin_amdgcn_s_sleep(1);
                wd = __hip_atomic_load(cp, __ATOMIC_RELAXED, __HIP_MEMORY_SCOPE_AGENT);
            }
            hbuf[pch] = __uint_as_float((unsigned)(wd >> 32));
        }
        __syncthreads();
        if (w == 0) rnn_lds[t][tid] = hbuf[tid];
    }

    if (w != 0) return;
    // ---- attention + MLP tail (role 0 only) ----
    watt_l[tid] = Watt[tid];
    if (tid < 64) wp2_l[tid] = Wp2[tid];
    __syncthreads();
    if (tid < T) {
        float sv = 0.0f;
        #pragma unroll 8
        for (int h = 0; h < H; h++) sv += rnn_lds[tid][h] * watt_l[h];
        sc[tid] = tanhf(sv + batt[0]);
    }
    __syncthreads();
    if (tid == 0) {
        float m = -1e30f;
        for (int t = 0; t < T; t++) m = fmaxf(m, sc[t]);
        float su = 0.0f;
        for (int t = 0; t < T; t++) { float e = expf(sc[t] - m); attw[t] = e; su += e; }
        float inv = 1.0f / su;
        for (int t = 0; t < T; t++) attw[t] *= inv;
    }
    __syncthreads();
    {
        float a = 0.0f;
        #pragma unroll
        for (int t = 0; t < T; t++) a += rnn_lds[t][tid] * attw[t];
        ctx_l[tid] = a;
    }
    __syncthreads();
    {
        int col2 = tid & 63, sl2 = tid >> 6;  // 4 k-slices of 64
        float a = 0.0f;
        #pragma unroll 16
        for (int kk = 0; kk < 64; kk++) {
            int k = sl2 * 64 + kk;
            a += ctx_l[k] * Wp1[k * 64 + col2];
        }
        part[tid] = a;
    }
    __syncthreads();
    if (tid < 64) {
        float a = bp1[tid] + part[tid] + part[64 + tid] + part[128 + tid] + part[192 + tid];
        hid_l[tid] = fmaxf(a, 0.0f);
    }
    __syncthreads();
    if (tid == 0) {
        float r = bp2[0];
        #pragma unroll
        for (int j = 0; j < 64; j++) r += hid_l[j] * wp2_l[j];
        out[0] = (r > 20.0f) ? r : log1pf(expf(r));
    }
}

extern "C" void kernel_launch(void* const* d_in, const int* in_sizes, int n_in,
                              void* d_out, int out_size, void* d_ws, size_t ws_size,
                              hipStream_t stream) {
    const float* x      = (const float*)d_in[0];
    const int*   ei     = (const int*)d_in[1];
    const float* fgate  = (const float*)d_in[2];
    const float* egate  = (const float*)d_in[3];
    const float* cached = (const float*)d_in[4];
    const float* Wproj  = (const float*)d_in[5];
    const float* bproj  = (const float*)d_in[6];
    const float* Wg1    = (const float*)d_in[7];
    const float* bg1    = (const float*)d_in[8];
    const float* Wg2    = (const float*)d_in[9];
    const float* bg2    = (const float*)d_in[10];
    const float* Wih    = (const float*)d_in[11];
    const float* Whh    = (const float*)d_in[12];
    const float* bih    = (const float*)d_in[13];
    const float* bhh    = (const float*)d_in[14];
    const float* Watt   = (const float*)d_in[15];
    const float* batt   = (const float*)d_in[16];
    const float* Wp1    = (const float*)d_in[17];
    const float* bp1    = (const float*)d_in[18];
    const float* Wp2    = (const float*)d_in[19];
    const float* bp2    = (const float*)d_in[20];
    const int*   ptgt   = (const int*)d_in[21];
    const int*   pepos  = (const int*)d_in[22];

    char* ws = (char*)d_ws;
    float* deg   = (float*)(ws + OFF_DEG);
    int*   cnt   = (int*)(ws + OFF_CNT);
    unsigned long long* comm = (unsigned long long*)(ws + OFF_COMM);
    unsigned char* fH1 = (unsigned char*)(ws + OFF_FH1);
    unsigned char* fP  = (unsigned char*)(ws + OFF_FP);
    int*   idxP  = (int*)(ws + OFF_IDXP);
    int*   idxH1 = (int*)(ws + OFF_IDXH1);
    int*   srcA  = (int*)(ws + OFF_SRCA);
    float* wA    = (float*)(ws + OFF_WA);
    int*   srcB  = (int*)(ws + OFF_SRCB);
    int*   dstB  = (int*)(ws + OFF_DSTB);
    float* wB    = (float*)(ws + OFF_WB);
    int*   listP = (int*)(ws + OFF_LISTP);
    int*   listH = (int*)(ws + OFF_LISTH);
    float* q     = (float*)(ws + OFF_Q);
    float* rs    = (float*)(ws + OFF_RS);
    float* emb   = (float*)(ws + OFF_EMB);
    float* xproj = (float*)(ws + OFF_XPROJ);

    hipMemsetAsync(ws, 0, ZERO_END, stream);

    int nEB = (E / 4 + 255) / 256;  // 782 blocks, int4-vectorized edge scans
    k_scan1<<<nEB, 256, 0, stream>>>(ei, egate, ptgt, cnt, fH1, srcA, wA, Whh);
    k_scan2<<<nEB, 256, 0, stream>>>(ei, egate, fH1, fP, cnt, srcB, dstB, wB, deg);
    k_scan3c<<<nEB, 256, 0, stream>>>(ei, egate, fH1, fP, deg, cnt, listP, listH, idxP, idxH1);
    k_pq_x<<<288, 256, 0, stream>>>(x, fgate, Wproj, bproj, Wg1, cnt, listP, q,
                                    cached, pepos, Wih, bih, bhh, xproj);
    k_h1<<<CAPH, 256, 0, stream>>>(ptgt, deg, cnt, listH, idxP, srcB, dstB, wB, q, bg1, Wg2, rs, emb);
    k_xpost<<<32, 256, 0, stream>>>(emb, ptgt, pepos, deg, cnt, idxH1, srcA, wA, rs, bg2,
                                    Wih, bih, bhh, xproj);
    k_lstm<<<32, 256, 0, stream>>>(Whh, xproj, comm, cnt + 4, Watt, batt, Wp1, bp1, Wp2, bp2,
                                   (float*)d_out);
}